// Round 11
// baseline (285.275 us; speedup 1.0000x reference)
//
#include <hip/hip_runtime.h>
#include <hip/hip_bf16.h>
#include <math.h>

#define B_ 64
#define L_ 512
#define D_ 768
#define J_ 31
#define S_ 32
#define H_ 100
#define G3 300
#define NC_ 10
#define EMB_ 50

__device__ __forceinline__ float sigmoidf_(float x) { return 1.0f / (1.0f + __expf(-x)); }
__device__ __forceinline__ float tanhf_(float x) {
    float e = __expf(2.0f * x);
    return 1.0f - 2.0f / (e + 1.0f);
}

typedef _Float16 half2_t __attribute__((ext_vector_type(2)));
__device__ __forceinline__ half2_t u_as_h2(unsigned u) { return __builtin_bit_cast(half2_t, u); }
__device__ __forceinline__ unsigned packh2(float a, float b) {
    half2_t p; p.x = (_Float16)a; p.y = (_Float16)b;
    return __builtin_bit_cast(unsigned, p);
}

// ---------------------------------------------------------------------------
// K1: per-clause softmax-weighted pooling.  One block per (s, b).
// ---------------------------------------------------------------------------
#define TCAP 18
__global__ __launch_bounds__(256) void pool_kernel(
    const float* __restrict__ hs, const int* __restrict__ cb,
    const float* __restrict__ fc5w, const float* __restrict__ fc5b,
    float* __restrict__ doc)
{
    __shared__ __align__(16) float tile[TCAP * D_];
    __shared__ float sc_s[L_];
    __shared__ float red[8];

    int s = blockIdx.x, b = blockIdx.y;
    int start = (s == 0) ? 0 : cb[b * J_ + s - 1];
    int end   = (s == J_) ? L_ : cb[b * J_ + s];
    int nt = end - start;
    int tid = threadIdx.x;

    if (nt <= 0) {
        for (int d = tid; d < D_; d += 256) doc[((size_t)s * B_ + b) * D_ + d] = 0.f;
        return;
    }
    bool staged = (nt <= TCAP);
    const float* base = hs + ((size_t)b * L_ + start) * D_;

    if (staged) {
        const float4* b4 = (const float4*)base;
        float4* t4 = (float4*)tile;
        int n4 = nt * (D_ / 4);
        for (int i = tid; i < n4; i += 256) t4[i] = b4[i];
    }
    int lane = tid & 63, wv = tid >> 6;
    float fw[12];
#pragma unroll
    for (int i = 0; i < 12; ++i) fw[i] = fc5w[i * 64 + lane];
    __syncthreads();

    for (int t = wv; t < nt; t += 4) {
        const float* row = staged ? &tile[t * D_] : (base + (size_t)t * D_);
        float p = 0.f;
#pragma unroll
        for (int i = 0; i < 12; ++i) p += row[i * 64 + lane] * fw[i];
        for (int off = 32; off; off >>= 1) p += __shfl_xor(p, off);
        if (lane == 0) sc_s[t] = p + fc5b[0];
    }
    __syncthreads();

    float lm = -INFINITY;
    for (int i = tid; i < nt; i += 256) lm = fmaxf(lm, sc_s[i]);
    for (int off = 32; off; off >>= 1) lm = fmaxf(lm, __shfl_xor(lm, off));
    if (lane == 0) red[wv] = lm;
    __syncthreads();
    float mx = fmaxf(fmaxf(red[0], red[1]), fmaxf(red[2], red[3]));
    float ls = 0.f;
    for (int i = tid; i < nt; i += 256) {
        float e = __expf(sc_s[i] - mx);
        sc_s[i] = e;
        ls += e;
    }
    for (int off = 32; off; off >>= 1) ls += __shfl_xor(ls, off);
    if (lane == 0) red[4 + wv] = ls;
    __syncthreads();
    float inv = 1.f / (red[4] + red[5] + red[6] + red[7]);

    float acc0 = 0.f, acc1 = 0.f, acc2 = 0.f;
    for (int t = 0; t < nt; ++t) {
        float w = sc_s[t] * inv;
        const float* row = staged ? &tile[t * D_] : (base + (size_t)t * D_);
        acc0 += w * row[tid];
        acc1 += w * row[256 + tid];
        acc2 += w * row[512 + tid];
    }
    float* o = doc + ((size_t)s * B_ + b) * D_;
    o[tid] = acc0; o[256 + tid] = acc1; o[512 + tid] = acc2;
}

// ---------------------------------------------------------------------------
// K2: gi = doc @ [Wf;Wb].T + [bf;bb]   M=2048, N=600, K=768  (64x64 tiles)
// ---------------------------------------------------------------------------
__global__ __launch_bounds__(256) void gemm_enc(
    const float* __restrict__ A,
    const float* __restrict__ Wf, const float* __restrict__ Wb,
    const float* __restrict__ bf_, const float* __restrict__ bb_,
    float* __restrict__ C)
{
    __shared__ __align__(16) float As[16][68];
    __shared__ __align__(16) float Ws[16][68];
    int n0 = blockIdx.x * 64, m0 = blockIdx.y * 64;
    int tid = threadIdx.x;
    int tx = tid & 15, ty = tid >> 4;
    int lr = tid >> 2, lk4 = tid & 3;
    float acc[4][4] = {};

    for (int kk = 0; kk < D_; kk += 16) {
        float4 av = *(const float4*)(A + ((size_t)(m0 + lr)) * D_ + kk + lk4 * 4);
        As[lk4 * 4 + 0][lr] = av.x; As[lk4 * 4 + 1][lr] = av.y;
        As[lk4 * 4 + 2][lr] = av.z; As[lk4 * 4 + 3][lr] = av.w;
        int n = n0 + lr;
        float4 wvv = make_float4(0.f, 0.f, 0.f, 0.f);
        if (n < G3)      wvv = *(const float4*)(Wf + (size_t)n * D_ + kk + lk4 * 4);
        else if (n < 600) wvv = *(const float4*)(Wb + (size_t)(n - G3) * D_ + kk + lk4 * 4);
        Ws[lk4 * 4 + 0][lr] = wvv.x; Ws[lk4 * 4 + 1][lr] = wvv.y;
        Ws[lk4 * 4 + 2][lr] = wvv.z; Ws[lk4 * 4 + 3][lr] = wvv.w;
        __syncthreads();
#pragma unroll
        for (int k = 0; k < 16; ++k) {
            float4 a4 = *(const float4*)&As[k][ty * 4];
            float4 w4 = *(const float4*)&Ws[k][tx * 4];
            float ai[4] = {a4.x, a4.y, a4.z, a4.w};
            float wj[4] = {w4.x, w4.y, w4.z, w4.w};
#pragma unroll
            for (int i = 0; i < 4; ++i)
#pragma unroll
                for (int j = 0; j < 4; ++j) acc[i][j] += ai[i] * wj[j];
        }
        __syncthreads();
    }
#pragma unroll
    for (int j = 0; j < 4; ++j) {
        int n = n0 + tx * 4 + j;
        if (n >= 600) continue;
        float bias = (n < G3) ? bf_[n] : bb_[n - G3];
#pragma unroll
        for (int i = 0; i < 4; ++i) {
            int m = m0 + ty * 4 + i;
            C[(size_t)m * 600 + n] = acc[i][j] + bias;
        }
    }
}

// ---------------------------------------------------------------------------
// Kpack: per-thread-contiguous packed-f16 Whh for the scans.
// wpack[m][tid][0..12]=wr, [13..25]=wz, [26..38]=wn, [39]=0.
// m: 0=enc_f, 1=enc_b, 2=dec.  Thread (j,q) covers k = 26q .. 26q+25.
// ---------------------------------------------------------------------------
__global__ __launch_bounds__(400) void pack_whh(
    const float* __restrict__ wf, const float* __restrict__ wb,
    const float* __restrict__ wd, unsigned* __restrict__ wpack)
{
    int m = blockIdx.x;
    const float* whh = (m == 0) ? wf : (m == 1) ? wb : wd;
    int tid = threadIdx.x;
    int j = tid >> 2, q = tid & 3;
    unsigned* o = wpack + (size_t)m * 16000 + (size_t)tid * 40;
#pragma unroll
    for (int d = 0; d < 13; ++d) {
        int k = 2 * (13 * q + d);
        float r0 = (k < H_) ? whh[j * H_ + k] : 0.f;
        float r1 = (k + 1 < H_) ? whh[j * H_ + k + 1] : 0.f;
        float z0 = (k < H_) ? whh[(100 + j) * H_ + k] : 0.f;
        float z1 = (k + 1 < H_) ? whh[(100 + j) * H_ + k + 1] : 0.f;
        float n0 = (k < H_) ? whh[(200 + j) * H_ + k] : 0.f;
        float n1 = (k + 1 < H_) ? whh[(200 + j) * H_ + k + 1] : 0.f;
        o[d]      = packh2(r0, r1);
        o[13 + d] = packh2(z0, z1);
        o[26 + d] = packh2(n0, n1);
    }
    o[39] = 0u;
}

// ---------------------------------------------------------------------------
// Scan core: weights PINNED in VGPRs (10 uint4 = 40 dwords of packed f16,
// loaded once from the per-thread-contiguous wpack, made opaque via asm so
// the compiler cannot rematerialize the loads inside the scan loop).
// h in LDS as 104-entry f16 (broadcast b32 reads, 4 distinct banks).
// ---------------------------------------------------------------------------
#define LOAD_WREGS(WPBASE)                                                  \
    uint4 wq[10];                                                           \
    if (mv) {                                                               \
        const uint4* wp_ = (const uint4*)((WPBASE) + (size_t)tid * 40);     \
        _Pragma("unroll")                                                   \
        for (int i = 0; i < 10; ++i) {                                      \
            wq[i] = wp_[i];                                                 \
            asm volatile("" : "+v"(wq[i].x), "+v"(wq[i].y),                 \
                              "+v"(wq[i].z), "+v"(wq[i].w));                \
        }                                                                   \
    }

#define WD(i) (((i) & 3) == 0 ? wq[(i) >> 2].x : ((i) & 3) == 1 ? wq[(i) >> 2].y \
             : ((i) & 3) == 2 ? wq[(i) >> 2].z : wq[(i) >> 2].w)

#define MATVEC_REG(PBUF)                                                    \
    {                                                                       \
        const unsigned* hh = (const unsigned*)(PBUF);                       \
        _Pragma("unroll")                                                   \
        for (int d = 0; d < 13; ++d) {                                      \
            half2_t hv = u_as_h2(hh[13 * q + d]);                           \
            ar = __builtin_amdgcn_fdot2(u_as_h2(WD(d)),      hv, ar, false); \
            az = __builtin_amdgcn_fdot2(u_as_h2(WD(13 + d)), hv, az, false); \
            an = __builtin_amdgcn_fdot2(u_as_h2(WD(26 + d)), hv, an, false); \
        }                                                                   \
        ar += __shfl_xor(ar, 1); ar += __shfl_xor(ar, 2);                   \
        az += __shfl_xor(az, 1); az += __shfl_xor(az, 2);                   \
        an += __shfl_xor(an, 1); an += __shfl_xor(an, 2);                   \
    }

// ---------------------------------------------------------------------------
// K3: encoder scans. 128 blocks = (b, dir), 448 threads (7 waves),
// ONE barrier per step (double-buffered f16 h).
// ---------------------------------------------------------------------------
#define ENCT 448
__global__ __launch_bounds__(ENCT, 1) void enc_scan(
    const float* __restrict__ gi, const unsigned* __restrict__ wpack,
    const float* __restrict__ bhh_f, const float* __restrict__ bhh_b,
    float* __restrict__ out1, float* __restrict__ hT)
{
    __shared__ __align__(8) _Float16 hhalf[2][104];

    int bid = blockIdx.x;
    int b = bid & 63;
    bool bwd = (bid >= 64);
    const float* bhh = bwd ? bhh_b : bhh_f;
    int tid = threadIdx.x;
    int j = tid >> 2, q = tid & 3;
    bool mv = tid < 400;

    if (tid < 104) { hhalf[0][tid] = (_Float16)0.f; hhalf[1][tid] = (_Float16)0.f; }
    LOAD_WREGS(wpack + (bwd ? 16000 : 0))
    float bhr = 0.f, bhz = 0.f, bhn = 0.f, hc = 0.f;
    if (mv && q == 0) { bhr = bhh[j]; bhz = bhh[100 + j]; bhn = bhh[200 + j]; }
    __syncthreads();

    const int goff = bwd ? G3 : 0;
    const int ooff = bwd ? H_ : 0;
    int p = 0;
    for (int step = 0; step < S_; ++step) {
        int t = bwd ? (S_ - 1 - step) : step;
        if (mv) {
            float ga0 = 0.f, ga1 = 0.f, ga2 = 0.f;
            if (q == 0) {
                const float* g = gi + ((size_t)t * B_ + b) * 600 + goff;
                ga0 = g[j]; ga1 = g[100 + j]; ga2 = g[200 + j];
            }
            float ar = 0.f, az = 0.f, an = 0.f;
            MATVEC_REG(hhalf[p])
            if (q == 0) {
                float r = sigmoidf_(ga0 + ar + bhr);
                float z = sigmoidf_(ga1 + az + bhz);
                float n = tanhf_(ga2 + r * (an + bhn));
                float hn = (1.f - z) * n + z * hc;
                hc = hn;
                hhalf[p ^ 1][j] = (_Float16)hn;
                out1[((size_t)t * B_ + b) * 200 + ooff + j] = hn;
            }
        }
        __syncthreads();
        p ^= 1;
    }
    if (!bwd && mv && q == 0) hT[b * H_ + j] = hc;
}

// ---------------------------------------------------------------------------
// K4a: W2[n] = dwih[n][50:150] @ l1w ; b2[n] ; tcg[c][n] = bih[n]+emb[c].dwih[n][0:50]
// ---------------------------------------------------------------------------
__global__ __launch_bounds__(256) void w2_precompute(
    const float* __restrict__ dwih, const float* __restrict__ l1w,
    const float* __restrict__ l1b, const float* __restrict__ emb,
    const float* __restrict__ bih,
    float* __restrict__ W2, float* __restrict__ b2, float* __restrict__ tcg)
{
    __shared__ float dw_s[H_];
    int n = blockIdx.x;
    int k = threadIdx.x;
    if (k < H_) dw_s[k] = dwih[(size_t)n * 150 + 50 + k];
    __syncthreads();
    if (k < 200) {
        float acc = 0.f;
        for (int i = 0; i < H_; ++i) acc += dw_s[i] * l1w[(size_t)i * 200 + k];
        W2[(size_t)n * 200 + k] = acc;
    } else if (k == 200) {
        float acc = 0.f;
        for (int i = 0; i < H_; ++i) acc += dw_s[i] * l1b[i];
        b2[n] = acc;
    } else if (k < 211) {
        int c = k - 201;
        float acc = bih[n];
        const float* er = emb + c * EMB_;
        const float* wr = dwih + (size_t)n * 150;
        for (int e = 0; e < EMB_; ++e) acc += er[e] * wr[e];
        tcg[c * G3 + n] = acc;
    }
}

// ---------------------------------------------------------------------------
// K4b: generic small NT GEMM
// ---------------------------------------------------------------------------
__global__ void small_gemm(
    const float* __restrict__ A, int lda, int K,
    const float* __restrict__ W, int wstride, int woff,
    const float* __restrict__ bias,
    float* __restrict__ C, int N, int ldc,
    int BM, int nChunk)
{
    extern __shared__ float sm[];
    int Kp = K + 1;
    float* Wl = sm;
    float* Al = sm + (size_t)nChunk * Kp;
    int nBase = blockIdx.x * nChunk;
    int nCnt = min(nChunk, N - nBase);
    int m0 = blockIdx.y * BM;

    for (int i = threadIdx.x; i < nCnt * K; i += blockDim.x) {
        int n = i / K, k = i - n * K;
        Wl[n * Kp + k] = W[(size_t)(nBase + n) * wstride + woff + k];
    }
    for (int i = threadIdx.x; i < BM * K; i += blockDim.x) {
        int mi = i / K, k = i - mi * K;
        Al[mi * Kp + k] = A[(size_t)(m0 + mi) * lda + k];
    }
    __syncthreads();

    for (int o = threadIdx.x; o < BM * nCnt; o += blockDim.x) {
        int mi = o / nCnt, n = o - mi * nCnt;
        const float* wr = &Wl[n * Kp];
        const float* ar = &Al[mi * Kp];
        float a0 = 0.f, a1 = 0.f, a2 = 0.f, a3 = 0.f;
        int k = 0;
        for (; k + 4 <= K; k += 4) {
            a0 += ar[k] * wr[k];
            a1 += ar[k + 1] * wr[k + 1];
            a2 += ar[k + 2] * wr[k + 2];
            a3 += ar[k + 3] * wr[k + 3];
        }
        for (; k < K; ++k) a0 += ar[k] * wr[k];
        float v = (a0 + a1) + (a2 + a3);
        if (bias) v += bias[nBase + n];
        C[(size_t)(m0 + mi) * ldc + nBase + n] = v;
    }
}

// ---------------------------------------------------------------------------
// K5: decoder scan. 64 blocks, 512 threads (8 waves).  Threads 0-399:
// pinned-register matvec + gates.  Wave 7: logits/argmax/log-softmax of
// step t-1 (f32 hf) concurrent with matvec.  2 barriers/step.
// ---------------------------------------------------------------------------
#define DECT 512
__global__ __launch_bounds__(DECT, 1) void dec_scan(
    const float* __restrict__ gi_lin, const unsigned* __restrict__ wpack,
    const float* __restrict__ bhh, const float* __restrict__ tcg,
    const float* __restrict__ h2lw, const float* __restrict__ h2lb,
    const float* __restrict__ hT, float* __restrict__ out)
{
    __shared__ float tc_s[NC_ * G3];               // 12 KB
    __shared__ float hl_s[NC_ * H_];               // 4 KB
    __shared__ __align__(8) _Float16 hhalf[2][104];
    __shared__ float hf[104];
    __shared__ int prev_s;

    int b = blockIdx.x;
    int tid = threadIdx.x;
    int j = tid >> 2, q = tid & 3;
    bool mv = tid < 400;

    for (int idx = tid; idx < NC_ * G3; idx += DECT) tc_s[idx] = tcg[idx];
    for (int idx = tid; idx < NC_ * H_; idx += DECT) hl_s[idx] = h2lw[idx];
    if (tid < 104) {
        float hv = (tid < H_) ? hT[b * H_ + tid] : 0.f;
        hf[tid] = hv;
        hhalf[0][tid] = (_Float16)hv;
        hhalf[1][tid] = (_Float16)0.f;
    }
    if (tid == 0) prev_s = 0;

    LOAD_WREGS(wpack + 32000)
    float bhr = 0.f, bhz = 0.f, bhn = 0.f, hc = 0.f;
    if (mv && q == 0) {
        bhr = bhh[j]; bhz = bhh[100 + j]; bhn = bhh[200 + j];
        hc = hT[b * H_ + j];
    }
    int l7 = tid - 448;                            // wave-7 lane if >= 0
    float hlb_r = (l7 >= 0 && l7 < NC_) ? h2lb[l7] : 0.f;
    __syncthreads();

    int p = 0;
    for (int t = 0; t <= S_; ++t) {
        float ga0 = 0.f, ga1 = 0.f, ga2 = 0.f;
        float ar = 0.f, az = 0.f, an = 0.f;
        if (mv) {
            if (t < S_) {
                if (q == 0) {
                    const float* g = gi_lin + ((size_t)t * B_ + b) * G3;
                    ga0 = g[j]; ga1 = g[100 + j]; ga2 = g[200 + j];
                }
                MATVEC_REG(hhalf[p])
            }
        } else if (l7 >= 0 && t >= 1) {
            // wave 7: logits for step t-1 from f32 hf
            float v = -INFINITY;
            if (l7 < 40) {
                int c = l7 >> 2, part = l7 & 3;
                float acc = 0.f;
                int k0 = 26 * part, k1 = (k0 + 26 < H_) ? k0 + 26 : H_;
                for (int k = k0; k < k1; ++k) acc += hl_s[c * H_ + k] * hf[k];
                acc += __shfl_xor(acc, 1);
                acc += __shfl_xor(acc, 2);
                v = acc;
            }
            float src = __shfl(v, (l7 < NC_) ? 4 * l7 : 0);
            float lv = (l7 < NC_) ? src + hlb_r : -INFINITY;
            float mx = lv; int am = (l7 < 16) ? l7 : 15;
#pragma unroll
            for (int m = 8; m; m >>= 1) {
                float ov = __shfl_xor(mx, m);
                int   oa = __shfl_xor(am, m);
                if (ov > mx || (ov == mx && oa < am)) { mx = ov; am = oa; }
            }
            float e = (l7 < NC_) ? __expf(lv - mx) : 0.f;
            float se = e;
#pragma unroll
            for (int m = 8; m; m >>= 1) se += __shfl_xor(se, m);
            float lse = mx + __logf(se);
            if (l7 < NC_) out[((size_t)(t - 1) * B_ + b) * NC_ + l7] = lv - lse;
            if (l7 == 0) prev_s = am;
        }
        __syncthreads();   // prev_s ready; hf consumed by logits
        if (t < S_ && mv && q == 0) {
            const float* tc = tc_s + prev_s * G3;
            float r = sigmoidf_(ga0 + tc[j]       + ar + bhr);
            float z = sigmoidf_(ga1 + tc[100 + j] + az + bhz);
            float n = tanhf_(   ga2 + tc[200 + j] + r * (an + bhn));
            float hn = (1.f - z) * n + z * hc;
            hc = hn;
            hf[j] = hn;
            hhalf[p ^ 1][j] = (_Float16)hn;
        }
        __syncthreads();   // h(t) visible for next matvec + logits
        p ^= 1;
    }
}

// ---------------------------------------------------------------------------
extern "C" void kernel_launch(void* const* d_in, const int* in_sizes, int n_in,
                              void* d_out, int out_size, void* d_ws, size_t ws_size,
                              hipStream_t stream)
{
    const float* hs   = (const float*)d_in[0];
    const int*   cb   = (const int*)  d_in[1];
    const float* fc5w = (const float*)d_in[2];
    const float* fc5b = (const float*)d_in[3];
    const float* ewif = (const float*)d_in[4];
    const float* ewhf = (const float*)d_in[5];
    const float* ebif = (const float*)d_in[6];
    const float* ebhf = (const float*)d_in[7];
    const float* ewib = (const float*)d_in[8];
    const float* ewhb = (const float*)d_in[9];
    const float* ebib = (const float*)d_in[10];
    const float* ebhb = (const float*)d_in[11];
    const float* emb  = (const float*)d_in[12];
    const float* l1w  = (const float*)d_in[13];
    const float* l1b  = (const float*)d_in[14];
    const float* dwih = (const float*)d_in[15];
    const float* dwhh = (const float*)d_in[16];
    const float* dbih = (const float*)d_in[17];
    const float* dbhh = (const float*)d_in[18];
    const float* h2lw = (const float*)d_in[19];
    const float* h2lb = (const float*)d_in[20];
    float* out = (float*)d_out;

    float* ws   = (float*)d_ws;
    float* doc  = ws;                  // [32*64, 768]   = 1572864
    float* gi   = doc  + 1572864;      // [2048, 600]    = 1228800
    float* out1 = gi   + 1228800;      // [2048, 200]    = 409600
    float* hT   = out1 + 409600;       // [64, 100]      = 6400
    float* W2   = hT   + 6400;         // [300, 200]     = 60000
    float* b2   = W2   + 60000;        // [300]
    float* tcg  = b2   + 320;          // [10, 300]      = 3000
    float* gil  = tcg  + 3072;         // [2048, 300]    = 614400
    unsigned* wpack = (unsigned*)(gil + 614400);  // 3 * 16000 dwords

    pool_kernel<<<dim3(S_, B_), 256, 0, stream>>>(hs, cb, fc5w, fc5b, doc);
    w2_precompute<<<G3, 256, 0, stream>>>(dwih, l1w, l1b, emb, dbih, W2, b2, tcg);
    pack_whh<<<3, 400, 0, stream>>>(ewhf, ewhb, dwhh, wpack);
    gemm_enc<<<dim3(10, 32), 256, 0, stream>>>(doc, ewif, ewib, ebif, ebib, gi);
    enc_scan<<<128, ENCT, 0, stream>>>(gi, wpack, ebhf, ebhb, out1, hT);
    {   // gil = out1 @ W2.T + b2   [2048,200]x[300,200] -> [2048,300]
        size_t sh = (size_t)(64 + 8) * 201 * sizeof(float);
        small_gemm<<<dim3(5, 256), 256, sh, stream>>>(out1, 200, 200,
                                                      W2, 200, 0, b2,
                                                      gil, 300, 300, 8, 64);
    }
    dec_scan<<<64, DECT, 0, stream>>>(gil, wpack, dbhh, tcg,
                                      h2lw, h2lb, hT, out);
}

// Round 12
// 269.801 us; speedup vs baseline: 1.0574x; 1.0574x over previous
//
#include <hip/hip_runtime.h>
#include <hip/hip_bf16.h>
#include <math.h>

#define B_ 64
#define L_ 512
#define D_ 768
#define J_ 31
#define S_ 32
#define H_ 100
#define G3 300
#define NC_ 10
#define EMB_ 50

__device__ __forceinline__ float sigmoidf_(float x) { return 1.0f / (1.0f + __expf(-x)); }
__device__ __forceinline__ float tanhf_(float x) {
    float e = __expf(2.0f * x);
    return 1.0f - 2.0f / (e + 1.0f);
}

typedef _Float16 half2_t __attribute__((ext_vector_type(2)));
__device__ __forceinline__ half2_t u_as_h2(unsigned u) { return __builtin_bit_cast(half2_t, u); }
__device__ __forceinline__ unsigned packh2(float a, float b) {
    half2_t p; p.x = (_Float16)a; p.y = (_Float16)b;
    return __builtin_bit_cast(unsigned, p);
}

// ---------------------------------------------------------------------------
// K1: per-clause softmax-weighted pooling.  One block per (s, b).
// ---------------------------------------------------------------------------
#define TCAP 18
__global__ __launch_bounds__(256) void pool_kernel(
    const float* __restrict__ hs, const int* __restrict__ cb,
    const float* __restrict__ fc5w, const float* __restrict__ fc5b,
    float* __restrict__ doc)
{
    __shared__ __align__(16) float tile[TCAP * D_];
    __shared__ float sc_s[L_];
    __shared__ float red[8];

    int s = blockIdx.x, b = blockIdx.y;
    int start = (s == 0) ? 0 : cb[b * J_ + s - 1];
    int end   = (s == J_) ? L_ : cb[b * J_ + s];
    int nt = end - start;
    int tid = threadIdx.x;

    if (nt <= 0) {
        for (int d = tid; d < D_; d += 256) doc[((size_t)s * B_ + b) * D_ + d] = 0.f;
        return;
    }
    bool staged = (nt <= TCAP);
    const float* base = hs + ((size_t)b * L_ + start) * D_;

    if (staged) {
        const float4* b4 = (const float4*)base;
        float4* t4 = (float4*)tile;
        int n4 = nt * (D_ / 4);
        for (int i = tid; i < n4; i += 256) t4[i] = b4[i];
    }
    int lane = tid & 63, wv = tid >> 6;
    float fw[12];
#pragma unroll
    for (int i = 0; i < 12; ++i) fw[i] = fc5w[i * 64 + lane];
    __syncthreads();

    for (int t = wv; t < nt; t += 4) {
        const float* row = staged ? &tile[t * D_] : (base + (size_t)t * D_);
        float p = 0.f;
#pragma unroll
        for (int i = 0; i < 12; ++i) p += row[i * 64 + lane] * fw[i];
        for (int off = 32; off; off >>= 1) p += __shfl_xor(p, off);
        if (lane == 0) sc_s[t] = p + fc5b[0];
    }
    __syncthreads();

    float lm = -INFINITY;
    for (int i = tid; i < nt; i += 256) lm = fmaxf(lm, sc_s[i]);
    for (int off = 32; off; off >>= 1) lm = fmaxf(lm, __shfl_xor(lm, off));
    if (lane == 0) red[wv] = lm;
    __syncthreads();
    float mx = fmaxf(fmaxf(red[0], red[1]), fmaxf(red[2], red[3]));
    float ls = 0.f;
    for (int i = tid; i < nt; i += 256) {
        float e = __expf(sc_s[i] - mx);
        sc_s[i] = e;
        ls += e;
    }
    for (int off = 32; off; off >>= 1) ls += __shfl_xor(ls, off);
    if (lane == 0) red[4 + wv] = ls;
    __syncthreads();
    float inv = 1.f / (red[4] + red[5] + red[6] + red[7]);

    float acc0 = 0.f, acc1 = 0.f, acc2 = 0.f;
    for (int t = 0; t < nt; ++t) {
        float w = sc_s[t] * inv;
        const float* row = staged ? &tile[t * D_] : (base + (size_t)t * D_);
        acc0 += w * row[tid];
        acc1 += w * row[256 + tid];
        acc2 += w * row[512 + tid];
    }
    float* o = doc + ((size_t)s * B_ + b) * D_;
    o[tid] = acc0; o[256 + tid] = acc1; o[512 + tid] = acc2;
}

// ---------------------------------------------------------------------------
// K2: gi = doc @ [Wf;Wb].T + [bf;bb]   M=2048, N=600, K=768  (64x64 tiles)
// ---------------------------------------------------------------------------
__global__ __launch_bounds__(256) void gemm_enc(
    const float* __restrict__ A,
    const float* __restrict__ Wf, const float* __restrict__ Wb,
    const float* __restrict__ bf_, const float* __restrict__ bb_,
    float* __restrict__ C)
{
    __shared__ __align__(16) float As[16][68];
    __shared__ __align__(16) float Ws[16][68];
    int n0 = blockIdx.x * 64, m0 = blockIdx.y * 64;
    int tid = threadIdx.x;
    int tx = tid & 15, ty = tid >> 4;
    int lr = tid >> 2, lk4 = tid & 3;
    float acc[4][4] = {};

    for (int kk = 0; kk < D_; kk += 16) {
        float4 av = *(const float4*)(A + ((size_t)(m0 + lr)) * D_ + kk + lk4 * 4);
        As[lk4 * 4 + 0][lr] = av.x; As[lk4 * 4 + 1][lr] = av.y;
        As[lk4 * 4 + 2][lr] = av.z; As[lk4 * 4 + 3][lr] = av.w;
        int n = n0 + lr;
        float4 wvv = make_float4(0.f, 0.f, 0.f, 0.f);
        if (n < G3)      wvv = *(const float4*)(Wf + (size_t)n * D_ + kk + lk4 * 4);
        else if (n < 600) wvv = *(const float4*)(Wb + (size_t)(n - G3) * D_ + kk + lk4 * 4);
        Ws[lk4 * 4 + 0][lr] = wvv.x; Ws[lk4 * 4 + 1][lr] = wvv.y;
        Ws[lk4 * 4 + 2][lr] = wvv.z; Ws[lk4 * 4 + 3][lr] = wvv.w;
        __syncthreads();
#pragma unroll
        for (int k = 0; k < 16; ++k) {
            float4 a4 = *(const float4*)&As[k][ty * 4];
            float4 w4 = *(const float4*)&Ws[k][tx * 4];
            float ai[4] = {a4.x, a4.y, a4.z, a4.w};
            float wj[4] = {w4.x, w4.y, w4.z, w4.w};
#pragma unroll
            for (int i = 0; i < 4; ++i)
#pragma unroll
                for (int j = 0; j < 4; ++j) acc[i][j] += ai[i] * wj[j];
        }
        __syncthreads();
    }
#pragma unroll
    for (int j = 0; j < 4; ++j) {
        int n = n0 + tx * 4 + j;
        if (n >= 600) continue;
        float bias = (n < G3) ? bf_[n] : bb_[n - G3];
#pragma unroll
        for (int i = 0; i < 4; ++i) {
            int m = m0 + ty * 4 + i;
            C[(size_t)m * 600 + n] = acc[i][j] + bias;
        }
    }
}

// ---------------------------------------------------------------------------
// Kpack: per-thread-contiguous packed-f16 Whh for the scans.
// ---------------------------------------------------------------------------
__global__ __launch_bounds__(400) void pack_whh(
    const float* __restrict__ wf, const float* __restrict__ wb,
    const float* __restrict__ wd, unsigned* __restrict__ wpack)
{
    int m = blockIdx.x;
    const float* whh = (m == 0) ? wf : (m == 1) ? wb : wd;
    int tid = threadIdx.x;
    int j = tid >> 2, q = tid & 3;
    unsigned* o = wpack + (size_t)m * 16000 + (size_t)tid * 40;
#pragma unroll
    for (int d = 0; d < 13; ++d) {
        int k = 2 * (13 * q + d);
        float r0 = (k < H_) ? whh[j * H_ + k] : 0.f;
        float r1 = (k + 1 < H_) ? whh[j * H_ + k + 1] : 0.f;
        float z0 = (k < H_) ? whh[(100 + j) * H_ + k] : 0.f;
        float z1 = (k + 1 < H_) ? whh[(100 + j) * H_ + k + 1] : 0.f;
        float n0 = (k < H_) ? whh[(200 + j) * H_ + k] : 0.f;
        float n1 = (k + 1 < H_) ? whh[(200 + j) * H_ + k + 1] : 0.f;
        o[d]      = packh2(r0, r1);
        o[13 + d] = packh2(z0, z1);
        o[26 + d] = packh2(n0, n1);
    }
    o[39] = 0u;
}

// ---------------------------------------------------------------------------
// Scan matvec core (same as r11; proven not the bottleneck).
// ---------------------------------------------------------------------------
#define LOAD_WREGS(WPBASE)                                                  \
    uint4 wq[10];                                                           \
    if (mv) {                                                               \
        const uint4* wp_ = (const uint4*)((WPBASE) + (size_t)tid * 40);     \
        _Pragma("unroll")                                                   \
        for (int i = 0; i < 10; ++i) wq[i] = wp_[i];                        \
    }

#define WD(i) (((i) & 3) == 0 ? wq[(i) >> 2].x : ((i) & 3) == 1 ? wq[(i) >> 2].y \
             : ((i) & 3) == 2 ? wq[(i) >> 2].z : wq[(i) >> 2].w)

#define MATVEC_REG(PBUF)                                                    \
    {                                                                       \
        const unsigned* hh = (const unsigned*)(PBUF);                       \
        _Pragma("unroll")                                                   \
        for (int d = 0; d < 13; ++d) {                                      \
            half2_t hv = u_as_h2(hh[13 * q + d]);                           \
            ar = __builtin_amdgcn_fdot2(u_as_h2(WD(d)),      hv, ar, false); \
            az = __builtin_amdgcn_fdot2(u_as_h2(WD(13 + d)), hv, az, false); \
            an = __builtin_amdgcn_fdot2(u_as_h2(WD(26 + d)), hv, an, false); \
        }                                                                   \
        ar += __shfl_xor(ar, 1); ar += __shfl_xor(ar, 2);                   \
        az += __shfl_xor(az, 1); az += __shfl_xor(az, 2);                   \
        an += __shfl_xor(an, 1); an += __shfl_xor(an, 2);                   \
    }

// ---------------------------------------------------------------------------
// K3: encoder scans. 256 blocks = 2x redundant copies of (b, dir); only
// bid<128 writes (DVFS probe: occupy all CUs).  448 threads, 1 barrier/step.
// ---------------------------------------------------------------------------
#define ENCT 448
__global__ __launch_bounds__(ENCT, 1) void enc_scan(
    const float* __restrict__ gi, const unsigned* __restrict__ wpack,
    const float* __restrict__ bhh_f, const float* __restrict__ bhh_b,
    float* __restrict__ out1, float* __restrict__ hT)
{
    __shared__ __align__(8) _Float16 hhalf[2][104];

    int bid = blockIdx.x;
    bool writer = bid < 128;
    int breal = bid & 127;
    int b = breal & 63;
    bool bwd = (breal >= 64);
    const float* bhh = bwd ? bhh_b : bhh_f;
    int tid = threadIdx.x;
    int j = tid >> 2, q = tid & 3;
    bool mv = tid < 400;

    if (tid < 104) { hhalf[0][tid] = (_Float16)0.f; hhalf[1][tid] = (_Float16)0.f; }
    LOAD_WREGS(wpack + (bwd ? 16000 : 0))
    float bhr = 0.f, bhz = 0.f, bhn = 0.f, hc = 0.f;
    if (mv && q == 0) { bhr = bhh[j]; bhz = bhh[100 + j]; bhn = bhh[200 + j]; }
    __syncthreads();

    const int goff = bwd ? G3 : 0;
    const int ooff = bwd ? H_ : 0;
    int p = 0;
    for (int step = 0; step < S_; ++step) {
        int t = bwd ? (S_ - 1 - step) : step;
        if (mv) {
            float ga0 = 0.f, ga1 = 0.f, ga2 = 0.f;
            if (q == 0) {
                const float* g = gi + ((size_t)t * B_ + b) * 600 + goff;
                ga0 = g[j]; ga1 = g[100 + j]; ga2 = g[200 + j];
            }
            float ar = 0.f, az = 0.f, an = 0.f;
            MATVEC_REG(hhalf[p])
            if (q == 0) {
                float r = sigmoidf_(ga0 + ar + bhr);
                float z = sigmoidf_(ga1 + az + bhz);
                float n = tanhf_(ga2 + r * (an + bhn));
                float hn = (1.f - z) * n + z * hc;
                hc = hn;
                hhalf[p ^ 1][j] = (_Float16)hn;
                if (writer) out1[((size_t)t * B_ + b) * 200 + ooff + j] = hn;
            }
        }
        __syncthreads();
        p ^= 1;
    }
    if (writer && !bwd && mv && q == 0) hT[b * H_ + j] = hc;
}

// ---------------------------------------------------------------------------
// K4a: W2[n] = dwih[n][50:150] @ l1w ; b2[n] ; tcg[c][n] = bih[n]+emb[c].dwih[n][0:50]
// ---------------------------------------------------------------------------
__global__ __launch_bounds__(256) void w2_precompute(
    const float* __restrict__ dwih, const float* __restrict__ l1w,
    const float* __restrict__ l1b, const float* __restrict__ emb,
    const float* __restrict__ bih,
    float* __restrict__ W2, float* __restrict__ b2, float* __restrict__ tcg)
{
    __shared__ float dw_s[H_];
    int n = blockIdx.x;
    int k = threadIdx.x;
    if (k < H_) dw_s[k] = dwih[(size_t)n * 150 + 50 + k];
    __syncthreads();
    if (k < 200) {
        float acc = 0.f;
        for (int i = 0; i < H_; ++i) acc += dw_s[i] * l1w[(size_t)i * 200 + k];
        W2[(size_t)n * 200 + k] = acc;
    } else if (k == 200) {
        float acc = 0.f;
        for (int i = 0; i < H_; ++i) acc += dw_s[i] * l1b[i];
        b2[n] = acc;
    } else if (k < 211) {
        int c = k - 201;
        float acc = bih[n];
        const float* er = emb + c * EMB_;
        const float* wr = dwih + (size_t)n * 150;
        for (int e = 0; e < EMB_; ++e) acc += er[e] * wr[e];
        tcg[c * G3 + n] = acc;
    }
}

// ---------------------------------------------------------------------------
// K4b: generic small NT GEMM
// ---------------------------------------------------------------------------
__global__ void small_gemm(
    const float* __restrict__ A, int lda, int K,
    const float* __restrict__ W, int wstride, int woff,
    const float* __restrict__ bias,
    float* __restrict__ C, int N, int ldc,
    int BM, int nChunk)
{
    extern __shared__ float sm[];
    int Kp = K + 1;
    float* Wl = sm;
    float* Al = sm + (size_t)nChunk * Kp;
    int nBase = blockIdx.x * nChunk;
    int nCnt = min(nChunk, N - nBase);
    int m0 = blockIdx.y * BM;

    for (int i = threadIdx.x; i < nCnt * K; i += blockDim.x) {
        int n = i / K, k = i - n * K;
        Wl[n * Kp + k] = W[(size_t)(nBase + n) * wstride + woff + k];
    }
    for (int i = threadIdx.x; i < BM * K; i += blockDim.x) {
        int mi = i / K, k = i - mi * K;
        Al[mi * Kp + k] = A[(size_t)(m0 + mi) * lda + k];
    }
    __syncthreads();

    for (int o = threadIdx.x; o < BM * nCnt; o += blockDim.x) {
        int mi = o / nCnt, n = o - mi * nCnt;
        const float* wr = &Wl[n * Kp];
        const float* ar = &Al[mi * Kp];
        float a0 = 0.f, a1 = 0.f, a2 = 0.f, a3 = 0.f;
        int k = 0;
        for (; k + 4 <= K; k += 4) {
            a0 += ar[k] * wr[k];
            a1 += ar[k + 1] * wr[k + 1];
            a2 += ar[k + 2] * wr[k + 2];
            a3 += ar[k + 3] * wr[k + 3];
        }
        for (; k < K; ++k) a0 += ar[k] * wr[k];
        float v = (a0 + a1) + (a2 + a3);
        if (bias) v += bias[nBase + n];
        C[(size_t)(m0 + mi) * ldc + nBase + n] = v;
    }
}

// ---------------------------------------------------------------------------
// K5: decoder scan. 256 blocks = 4x redundant copies (bid&63 = batch elem,
// only bid<64 writes).  448 threads (7 waves).  ONE barrier/step: every
// wave computes the 10-class logits+argmax of step t-1 REDUNDANTLY
// (deterministic -> identical prev in-register, no cross-wave handoff).
// ---------------------------------------------------------------------------
#define DECT 448
__global__ __launch_bounds__(DECT, 1) void dec_scan(
    const float* __restrict__ gi_lin, const unsigned* __restrict__ wpack,
    const float* __restrict__ bhh, const float* __restrict__ tcg,
    const float* __restrict__ h2lw, const float* __restrict__ h2lb,
    const float* __restrict__ hT, float* __restrict__ out)
{
    __shared__ float tc_s[NC_ * G3];               // 12 KB
    __shared__ float hl_s[NC_ * H_];               // 4 KB
    __shared__ __align__(8) _Float16 hhalf[2][104];
    __shared__ __align__(16) float hf[2][104];

    int bid = blockIdx.x;
    bool writer = bid < 64;
    int b = bid & 63;
    int tid = threadIdx.x;
    int j = tid >> 2, q = tid & 3;
    bool mv = tid < 400;
    int lane = tid & 63;
    bool w0 = writer && (tid < 64);                // writer wave

    for (int idx = tid; idx < NC_ * G3; idx += DECT) tc_s[idx] = tcg[idx];
    for (int idx = tid; idx < NC_ * H_; idx += DECT) hl_s[idx] = h2lw[idx];
    if (tid < 104) {
        float hv = (tid < H_) ? hT[b * H_ + tid] : 0.f;
        hf[0][tid] = hv;            hf[1][tid] = 0.f;
        hhalf[0][tid] = (_Float16)hv; hhalf[1][tid] = (_Float16)0.f;
    }
    LOAD_WREGS(wpack + 32000)
    float bhr = 0.f, bhz = 0.f, bhn = 0.f, hc = 0.f;
    if (mv && q == 0) {
        bhr = bhh[j]; bhz = bhh[100 + j]; bhn = bhh[200 + j];
        hc = hT[b * H_ + j];
    }
    float hlb_r = (lane < NC_) ? h2lb[lane] : 0.f;
    int prev = 0;
    __syncthreads();

    int p = 0;
    for (int t = 0; t <= S_; ++t) {
        float ga0 = 0.f, ga1 = 0.f, ga2 = 0.f;
        float ar = 0.f, az = 0.f, an = 0.f;
        if (t < S_ && mv) {
            if (q == 0) {
                const float* g = gi_lin + ((size_t)t * B_ + b) * G3;
                ga0 = g[j]; ga1 = g[100 + j]; ga2 = g[200 + j];
            }
            MATVEC_REG(hhalf[p])
        }
        if (t >= 1) {
            // redundant logits/argmax of step t-1, per wave (h(t-1) = hf[p])
            float acc = 0.f;
            if (lane < 40) {
                int c = lane >> 2, part = lane & 3;
                const float* hr = hl_s + c * H_;
                const float* hv = hf[p];
                int k0 = 25 * part;
                for (int k = k0; k < k0 + 25; ++k) acc += hr[k] * hv[k];
                acc += __shfl_xor(acc, 1);
                acc += __shfl_xor(acc, 2);
            }
            float src = __shfl(acc, (lane < NC_) ? 4 * lane : 0);
            float lv = (lane < NC_) ? src + hlb_r : -INFINITY;
            float mx = lv; int am = lane & 15;
#pragma unroll
            for (int m = 8; m; m >>= 1) {          // 16-lane group reduce
                float ov = __shfl_xor(mx, m);
                int   oa = __shfl_xor(am, m);
                if (ov > mx || (ov == mx && oa < am)) { mx = ov; am = oa; }
            }
            float e = (lane < NC_) ? __expf(lv - mx) : 0.f;
            float se = e;
#pragma unroll
            for (int m = 8; m; m >>= 1) se += __shfl_xor(se, m);
            if (w0 && lane < NC_) {
                float lse = mx + __logf(se);
                out[((size_t)(t - 1) * B_ + b) * NC_ + lane] = lv - lse;
            }
            prev = __shfl(am, 0);                  // whole wave gets group-0 result
        }
        // gates: same wave as its own argmax -> no barrier in between
        if (t < S_ && mv && q == 0) {
            const float* tc = tc_s + prev * G3;
            float r = sigmoidf_(ga0 + tc[j]       + ar + bhr);
            float z = sigmoidf_(ga1 + tc[100 + j] + az + bhz);
            float n = tanhf_(   ga2 + tc[200 + j] + r * (an + bhn));
            float hn = (1.f - z) * n + z * hc;
            hc = hn;
            hf[p ^ 1][j] = hn;
            hhalf[p ^ 1][j] = (_Float16)hn;
        }
        __syncthreads();   // publish h(t); ONE barrier per step
        p ^= 1;
    }
}

// ---------------------------------------------------------------------------
extern "C" void kernel_launch(void* const* d_in, const int* in_sizes, int n_in,
                              void* d_out, int out_size, void* d_ws, size_t ws_size,
                              hipStream_t stream)
{
    const float* hs   = (const float*)d_in[0];
    const int*   cb   = (const int*)  d_in[1];
    const float* fc5w = (const float*)d_in[2];
    const float* fc5b = (const float*)d_in[3];
    const float* ewif = (const float*)d_in[4];
    const float* ewhf = (const float*)d_in[5];
    const float* ebif = (const float*)d_in[6];
    const float* ebhf = (const float*)d_in[7];
    const float* ewib = (const float*)d_in[8];
    const float* ewhb = (const float*)d_in[9];
    const float* ebib = (const float*)d_in[10];
    const float* ebhb = (const float*)d_in[11];
    const float* emb  = (const float*)d_in[12];
    const float* l1w  = (const float*)d_in[13];
    const float* l1b  = (const float*)d_in[14];
    const float* dwih = (const float*)d_in[15];
    const float* dwhh = (const float*)d_in[16];
    const float* dbih = (const float*)d_in[17];
    const float* dbhh = (const float*)d_in[18];
    const float* h2lw = (const float*)d_in[19];
    const float* h2lb = (const float*)d_in[20];
    float* out = (float*)d_out;

    float* ws   = (float*)d_ws;
    float* doc  = ws;                  // [32*64, 768]   = 1572864
    float* gi   = doc  + 1572864;      // [2048, 600]    = 1228800
    float* out1 = gi   + 1228800;      // [2048, 200]    = 409600
    float* hT   = out1 + 409600;       // [64, 100]      = 6400
    float* W2   = hT   + 6400;         // [300, 200]     = 60000
    float* b2   = W2   + 60000;        // [300]
    float* tcg  = b2   + 320;          // [10, 300]      = 3000
    float* gil  = tcg  + 3072;         // [2048, 300]    = 614400
    unsigned* wpack = (unsigned*)(gil + 614400);  // 3 * 16000 dwords

    pool_kernel<<<dim3(S_, B_), 256, 0, stream>>>(hs, cb, fc5w, fc5b, doc);
    w2_precompute<<<G3, 256, 0, stream>>>(dwih, l1w, l1b, emb, dbih, W2, b2, tcg);
    pack_whh<<<3, 400, 0, stream>>>(ewhf, ewhb, dwhh, wpack);
    gemm_enc<<<dim3(10, 32), 256, 0, stream>>>(doc, ewif, ewib, ebif, ebib, gi);
    enc_scan<<<256, ENCT, 0, stream>>>(gi, wpack, ebhf, ebhb, out1, hT);
    {   // gil = out1 @ W2.T + b2   [2048,200]x[300,200] -> [2048,300]
        size_t sh = (size_t)(64 + 8) * 201 * sizeof(float);
        small_gemm<<<dim3(5, 256), 256, sh, stream>>>(out1, 200, 200,
                                                      W2, 200, 0, b2,
                                                      gil, 300, 300, 8, 64);
    }
    dec_scan<<<256, DECT, 0, stream>>>(gil, wpack, dbhh, tcg,
                                       h2lw, h2lb, hT, out);
}

// Round 13
// 194.648 us; speedup vs baseline: 1.4656x; 1.3861x over previous
//
#include <hip/hip_runtime.h>
#include <hip/hip_bf16.h>
#include <math.h>

#define B_ 64
#define L_ 512
#define D_ 768
#define J_ 31
#define S_ 32
#define H_ 100
#define G3 300
#define NC_ 10
#define EMB_ 50

__device__ __forceinline__ float sigmoidf_(float x) { return 1.0f / (1.0f + __expf(-x)); }
__device__ __forceinline__ float tanhf_(float x) {
    float e = __expf(2.0f * x);
    return 1.0f - 2.0f / (e + 1.0f);
}

typedef _Float16 half2_t __attribute__((ext_vector_type(2)));
__device__ __forceinline__ half2_t u_as_h2(unsigned u) { return __builtin_bit_cast(half2_t, u); }
__device__ __forceinline__ unsigned packh2(float a, float b) {
    half2_t p; p.x = (_Float16)a; p.y = (_Float16)b;
    return __builtin_bit_cast(unsigned, p);
}

// ---------------------------------------------------------------------------
// K1: per-clause softmax-weighted pooling.  One block per (s, b).
// ---------------------------------------------------------------------------
#define TCAP 18
__global__ __launch_bounds__(256) void pool_kernel(
    const float* __restrict__ hs, const int* __restrict__ cb,
    const float* __restrict__ fc5w, const float* __restrict__ fc5b,
    float* __restrict__ doc)
{
    __shared__ __align__(16) float tile[TCAP * D_];
    __shared__ float sc_s[L_];
    __shared__ float red[8];

    int s = blockIdx.x, b = blockIdx.y;
    int start = (s == 0) ? 0 : cb[b * J_ + s - 1];
    int end   = (s == J_) ? L_ : cb[b * J_ + s];
    int nt = end - start;
    int tid = threadIdx.x;

    if (nt <= 0) {
        for (int d = tid; d < D_; d += 256) doc[((size_t)s * B_ + b) * D_ + d] = 0.f;
        return;
    }
    bool staged = (nt <= TCAP);
    const float* base = hs + ((size_t)b * L_ + start) * D_;

    if (staged) {
        const float4* b4 = (const float4*)base;
        float4* t4 = (float4*)tile;
        int n4 = nt * (D_ / 4);
        for (int i = tid; i < n4; i += 256) t4[i] = b4[i];
    }
    int lane = tid & 63, wv = tid >> 6;
    float fw[12];
#pragma unroll
    for (int i = 0; i < 12; ++i) fw[i] = fc5w[i * 64 + lane];
    __syncthreads();

    for (int t = wv; t < nt; t += 4) {
        const float* row = staged ? &tile[t * D_] : (base + (size_t)t * D_);
        float p = 0.f;
#pragma unroll
        for (int i = 0; i < 12; ++i) p += row[i * 64 + lane] * fw[i];
        for (int off = 32; off; off >>= 1) p += __shfl_xor(p, off);
        if (lane == 0) sc_s[t] = p + fc5b[0];
    }
    __syncthreads();

    float lm = -INFINITY;
    for (int i = tid; i < nt; i += 256) lm = fmaxf(lm, sc_s[i]);
    for (int off = 32; off; off >>= 1) lm = fmaxf(lm, __shfl_xor(lm, off));
    if (lane == 0) red[wv] = lm;
    __syncthreads();
    float mx = fmaxf(fmaxf(red[0], red[1]), fmaxf(red[2], red[3]));
    float ls = 0.f;
    for (int i = tid; i < nt; i += 256) {
        float e = __expf(sc_s[i] - mx);
        sc_s[i] = e;
        ls += e;
    }
    for (int off = 32; off; off >>= 1) ls += __shfl_xor(ls, off);
    if (lane == 0) red[4 + wv] = ls;
    __syncthreads();
    float inv = 1.f / (red[4] + red[5] + red[6] + red[7]);

    float acc0 = 0.f, acc1 = 0.f, acc2 = 0.f;
    for (int t = 0; t < nt; ++t) {
        float w = sc_s[t] * inv;
        const float* row = staged ? &tile[t * D_] : (base + (size_t)t * D_);
        acc0 += w * row[tid];
        acc1 += w * row[256 + tid];
        acc2 += w * row[512 + tid];
    }
    float* o = doc + ((size_t)s * B_ + b) * D_;
    o[tid] = acc0; o[256 + tid] = acc1; o[512 + tid] = acc2;
}

// ---------------------------------------------------------------------------
// K2: gi = doc @ [Wf;Wb].T + bias via f16 dot2 (pack during staging).
// M=2048, N=600, K=768 (= 384 f16 pairs, 24 chunks of 16 pairs).
// ---------------------------------------------------------------------------
__global__ __launch_bounds__(256) void gemm_enc(
    const float* __restrict__ A,
    const float* __restrict__ Wf, const float* __restrict__ Wb,
    const float* __restrict__ bf_, const float* __restrict__ bb_,
    float* __restrict__ C)
{
    __shared__ __align__(16) unsigned As[16][68];
    __shared__ __align__(16) unsigned Ws[16][68];
    int n0 = blockIdx.x * 64, m0 = blockIdx.y * 64;
    int tid = threadIdx.x;
    int tx = tid & 15, ty = tid >> 4;
    int lr = tid >> 2, lk4 = tid & 3;
    float acc[4][4] = {};

    for (int kk = 0; kk < 384; kk += 16) {
        {
            const float* ap = A + ((size_t)(m0 + lr)) * D_ + (kk + lk4 * 4) * 2;
            float4 x = *(const float4*)ap;
            float4 y = *(const float4*)(ap + 4);
            As[lk4 * 4 + 0][lr] = packh2(x.x, x.y);
            As[lk4 * 4 + 1][lr] = packh2(x.z, x.w);
            As[lk4 * 4 + 2][lr] = packh2(y.x, y.y);
            As[lk4 * 4 + 3][lr] = packh2(y.z, y.w);
            int n = n0 + lr;
            float4 u = make_float4(0.f, 0.f, 0.f, 0.f);
            float4 v = make_float4(0.f, 0.f, 0.f, 0.f);
            if (n < G3) {
                const float* wp = Wf + (size_t)n * D_ + (kk + lk4 * 4) * 2;
                u = *(const float4*)wp; v = *(const float4*)(wp + 4);
            } else if (n < 600) {
                const float* wp = Wb + (size_t)(n - G3) * D_ + (kk + lk4 * 4) * 2;
                u = *(const float4*)wp; v = *(const float4*)(wp + 4);
            }
            Ws[lk4 * 4 + 0][lr] = packh2(u.x, u.y);
            Ws[lk4 * 4 + 1][lr] = packh2(u.z, u.w);
            Ws[lk4 * 4 + 2][lr] = packh2(v.x, v.y);
            Ws[lk4 * 4 + 3][lr] = packh2(v.z, v.w);
        }
        __syncthreads();
#pragma unroll
        for (int ku = 0; ku < 16; ++ku) {
            uint4 av = *(const uint4*)&As[ku][ty * 4];
            uint4 wv = *(const uint4*)&Ws[ku][tx * 4];
            unsigned aa[4] = {av.x, av.y, av.z, av.w};
            unsigned ww[4] = {wv.x, wv.y, wv.z, wv.w};
#pragma unroll
            for (int i = 0; i < 4; ++i)
#pragma unroll
                for (int jj = 0; jj < 4; ++jj)
                    acc[i][jj] = __builtin_amdgcn_fdot2(u_as_h2(aa[i]), u_as_h2(ww[jj]),
                                                        acc[i][jj], false);
        }
        __syncthreads();
    }
#pragma unroll
    for (int jj = 0; jj < 4; ++jj) {
        int n = n0 + tx * 4 + jj;
        if (n >= 600) continue;
        float bias = (n < G3) ? bf_[n] : bb_[n - G3];
#pragma unroll
        for (int i = 0; i < 4; ++i) {
            int m = m0 + ty * 4 + i;
            C[(size_t)m * 600 + n] = acc[i][jj] + bias;
        }
    }
}

// ---------------------------------------------------------------------------
// K2b: gil = out1 @ W2.T + b2.  M=2048, N=300, K=200, f32 64x64 tiles.
// ---------------------------------------------------------------------------
__global__ __launch_bounds__(256) void gemm_gil(
    const float* __restrict__ A,      // [2048][200]
    const float* __restrict__ W,      // [300][200]
    const float* __restrict__ bias,   // [300]
    float* __restrict__ C)            // [2048][300]
{
    __shared__ __align__(16) float As[16][68];
    __shared__ __align__(16) float Ws[16][68];
    int n0 = blockIdx.x * 64, m0 = blockIdx.y * 64;
    int tid = threadIdx.x;
    int tx = tid & 15, ty = tid >> 4;
    int lr = tid >> 2, lk4 = tid & 3;
    float acc[4][4] = {};

    for (int kk = 0; kk < 208; kk += 16) {
        int k = kk + lk4 * 4;
        float4 av = make_float4(0.f, 0.f, 0.f, 0.f);
        if (k < 200) av = *(const float4*)(A + (size_t)(m0 + lr) * 200 + k);
        As[lk4 * 4 + 0][lr] = av.x; As[lk4 * 4 + 1][lr] = av.y;
        As[lk4 * 4 + 2][lr] = av.z; As[lk4 * 4 + 3][lr] = av.w;
        int n = n0 + lr;
        float4 wv = make_float4(0.f, 0.f, 0.f, 0.f);
        if (n < G3 && k < 200) wv = *(const float4*)(W + (size_t)n * 200 + k);
        Ws[lk4 * 4 + 0][lr] = wv.x; Ws[lk4 * 4 + 1][lr] = wv.y;
        Ws[lk4 * 4 + 2][lr] = wv.z; Ws[lk4 * 4 + 3][lr] = wv.w;
        __syncthreads();
#pragma unroll
        for (int ki = 0; ki < 16; ++ki) {
            float4 a4 = *(const float4*)&As[ki][ty * 4];
            float4 w4 = *(const float4*)&Ws[ki][tx * 4];
            float ai[4] = {a4.x, a4.y, a4.z, a4.w};
            float wj[4] = {w4.x, w4.y, w4.z, w4.w};
#pragma unroll
            for (int i = 0; i < 4; ++i)
#pragma unroll
                for (int jj = 0; jj < 4; ++jj) acc[i][jj] += ai[i] * wj[jj];
        }
        __syncthreads();
    }
#pragma unroll
    for (int jj = 0; jj < 4; ++jj) {
        int n = n0 + tx * 4 + jj;
        if (n >= G3) continue;
#pragma unroll
        for (int i = 0; i < 4; ++i) {
            int m = m0 + ty * 4 + i;
            C[(size_t)m * G3 + n] = acc[i][jj] + bias[n];
        }
    }
}

// ---------------------------------------------------------------------------
// Kpack: per-thread-contiguous packed-f16 Whh for the scans.
// ---------------------------------------------------------------------------
__global__ __launch_bounds__(400) void pack_whh(
    const float* __restrict__ wf, const float* __restrict__ wb,
    const float* __restrict__ wd, unsigned* __restrict__ wpack)
{
    int m = blockIdx.x;
    const float* whh = (m == 0) ? wf : (m == 1) ? wb : wd;
    int tid = threadIdx.x;
    int j = tid >> 2, q = tid & 3;
    unsigned* o = wpack + (size_t)m * 16000 + (size_t)tid * 40;
#pragma unroll
    for (int d = 0; d < 13; ++d) {
        int k = 2 * (13 * q + d);
        float r0 = (k < H_) ? whh[j * H_ + k] : 0.f;
        float r1 = (k + 1 < H_) ? whh[j * H_ + k + 1] : 0.f;
        float z0 = (k < H_) ? whh[(100 + j) * H_ + k] : 0.f;
        float z1 = (k + 1 < H_) ? whh[(100 + j) * H_ + k + 1] : 0.f;
        float n0 = (k < H_) ? whh[(200 + j) * H_ + k] : 0.f;
        float n1 = (k + 1 < H_) ? whh[(200 + j) * H_ + k + 1] : 0.f;
        o[d]      = packh2(r0, r1);
        o[13 + d] = packh2(z0, z1);
        o[26 + d] = packh2(n0, n1);
    }
    o[39] = 0u;
}

// ---------------------------------------------------------------------------
// Scan matvec core.
// ---------------------------------------------------------------------------
#define LOAD_WREGS(WPBASE)                                                  \
    uint4 wq[10];                                                           \
    if (mv) {                                                               \
        const uint4* wp_ = (const uint4*)((WPBASE) + (size_t)tid * 40);     \
        _Pragma("unroll")                                                   \
        for (int i = 0; i < 10; ++i) wq[i] = wp_[i];                        \
    }

#define WD(i) (((i) & 3) == 0 ? wq[(i) >> 2].x : ((i) & 3) == 1 ? wq[(i) >> 2].y \
             : ((i) & 3) == 2 ? wq[(i) >> 2].z : wq[(i) >> 2].w)

#define MATVEC_REG(PBUF)                                                    \
    {                                                                       \
        const unsigned* hh = (const unsigned*)(PBUF);                       \
        _Pragma("unroll")                                                   \
        for (int d = 0; d < 13; ++d) {                                      \
            half2_t hv = u_as_h2(hh[13 * q + d]);                           \
            ar = __builtin_amdgcn_fdot2(u_as_h2(WD(d)),      hv, ar, false); \
            az = __builtin_amdgcn_fdot2(u_as_h2(WD(13 + d)), hv, az, false); \
            an = __builtin_amdgcn_fdot2(u_as_h2(WD(26 + d)), hv, an, false); \
        }                                                                   \
        ar += __shfl_xor(ar, 1); ar += __shfl_xor(ar, 2);                   \
        az += __shfl_xor(az, 1); az += __shfl_xor(az, 2);                   \
        an += __shfl_xor(an, 1); an += __shfl_xor(an, 2);                   \
    }

// ---------------------------------------------------------------------------
// K3: encoder scans. 256 blocks (2x redundant; bid<128 writes), 448 thr,
// 1 barrier/step, unroll-2 with next-step g prefetch into named regs.
// ---------------------------------------------------------------------------
#define ENCT 448
#define ENC_SUB(GA0, GA1, GA2, NB0, NB1, NB2, SC, SN)                       \
    {                                                                       \
        if (mv) {                                                           \
            if (q == 0 && (SN) < S_) {                                      \
                int tn_ = bwd ? (S_ - 1 - (SN)) : (SN);                     \
                const float* gg_ = gi + ((size_t)tn_ * B_ + b) * 600 + goff; \
                NB0 = gg_[j]; NB1 = gg_[100 + j]; NB2 = gg_[200 + j];       \
            }                                                               \
            float ar = 0.f, az = 0.f, an = 0.f;                             \
            MATVEC_REG(hhalf[p])                                            \
            if (q == 0) {                                                   \
                int tc_ = bwd ? (S_ - 1 - (SC)) : (SC);                     \
                float r = sigmoidf_(GA0 + ar + bhr);                        \
                float z = sigmoidf_(GA1 + az + bhz);                        \
                float n = tanhf_(GA2 + r * (an + bhn));                     \
                float hn = (1.f - z) * n + z * hc;                          \
                hc = hn;                                                    \
                hhalf[p ^ 1][j] = (_Float16)hn;                             \
                if (writer) out1[((size_t)tc_ * B_ + b) * 200 + ooff + j] = hn; \
            }                                                               \
        }                                                                   \
        __syncthreads();                                                    \
        p ^= 1;                                                             \
    }

__global__ __launch_bounds__(ENCT, 1) void enc_scan(
    const float* __restrict__ gi, const unsigned* __restrict__ wpack,
    const float* __restrict__ bhh_f, const float* __restrict__ bhh_b,
    float* __restrict__ out1, float* __restrict__ hT)
{
    __shared__ __align__(8) _Float16 hhalf[2][104];

    int bid = blockIdx.x;
    bool writer = bid < 128;
    int breal = bid & 127;
    int b = breal & 63;
    bool bwd = (breal >= 64);
    const float* bhh = bwd ? bhh_b : bhh_f;
    int tid = threadIdx.x;
    int j = tid >> 2, q = tid & 3;
    bool mv = tid < 400;
    const int goff = bwd ? G3 : 0;
    const int ooff = bwd ? H_ : 0;

    if (tid < 104) { hhalf[0][tid] = (_Float16)0.f; hhalf[1][tid] = (_Float16)0.f; }
    LOAD_WREGS(wpack + (bwd ? 16000 : 0))
    float bhr = 0.f, bhz = 0.f, bhn = 0.f, hc = 0.f;
    float pA0 = 0.f, pA1 = 0.f, pA2 = 0.f, pB0 = 0.f, pB1 = 0.f, pB2 = 0.f;
    if (mv && q == 0) {
        bhr = bhh[j]; bhz = bhh[100 + j]; bhn = bhh[200 + j];
        int t0 = bwd ? (S_ - 1) : 0;
        const float* gg = gi + ((size_t)t0 * B_ + b) * 600 + goff;
        pA0 = gg[j]; pA1 = gg[100 + j]; pA2 = gg[200 + j];
    }
    __syncthreads();

    int p = 0;
    for (int step = 0; step < S_; step += 2) {
        ENC_SUB(pA0, pA1, pA2, pB0, pB1, pB2, step, step + 1)
        ENC_SUB(pB0, pB1, pB2, pA0, pA1, pA2, step + 1, step + 2)
    }
    if (writer && !bwd && mv && q == 0) hT[b * H_ + j] = hc;
}

// ---------------------------------------------------------------------------
// K4a: W2[n] = dwih[n][50:150] @ l1w ; b2[n] ; tcg[c][n] = bih[n]+emb[c].dwih[n][0:50]
// ---------------------------------------------------------------------------
__global__ __launch_bounds__(256) void w2_precompute(
    const float* __restrict__ dwih, const float* __restrict__ l1w,
    const float* __restrict__ l1b, const float* __restrict__ emb,
    const float* __restrict__ bih,
    float* __restrict__ W2, float* __restrict__ b2, float* __restrict__ tcg)
{
    __shared__ float dw_s[H_];
    int n = blockIdx.x;
    int k = threadIdx.x;
    if (k < H_) dw_s[k] = dwih[(size_t)n * 150 + 50 + k];
    __syncthreads();
    if (k < 200) {
        float acc = 0.f;
        for (int i = 0; i < H_; ++i) acc += dw_s[i] * l1w[(size_t)i * 200 + k];
        W2[(size_t)n * 200 + k] = acc;
    } else if (k == 200) {
        float acc = 0.f;
        for (int i = 0; i < H_; ++i) acc += dw_s[i] * l1b[i];
        b2[n] = acc;
    } else if (k < 211) {
        int c = k - 201;
        float acc = bih[n];
        const float* er = emb + c * EMB_;
        const float* wr = dwih + (size_t)n * 150;
        for (int e = 0; e < EMB_; ++e) acc += er[e] * wr[e];
        tcg[c * G3 + n] = acc;
    }
}

// ---------------------------------------------------------------------------
// K5: decoder scan. 256 blocks (4x redundant; bid<64 writes), 448 thr,
// 1 barrier/step, redundant per-wave logits/argmax, unroll-2 g prefetch.
// ---------------------------------------------------------------------------
#define DECT 448
#define DEC_LOGITS(TPREV)                                                   \
    {                                                                       \
        float acc_ = 0.f;                                                   \
        if (lane < 40) {                                                    \
            int c_ = lane >> 2, part_ = lane & 3;                           \
            const float* hr_ = hl_s + c_ * H_;                              \
            const float* hv_ = hf[p];                                       \
            int k0_ = 25 * part_;                                           \
            for (int k_ = k0_; k_ < k0_ + 25; ++k_) acc_ += hr_[k_] * hv_[k_]; \
            acc_ += __shfl_xor(acc_, 1);                                    \
            acc_ += __shfl_xor(acc_, 2);                                    \
        }                                                                   \
        float src_ = __shfl(acc_, (lane < NC_) ? 4 * lane : 0);             \
        float lv_ = (lane < NC_) ? src_ + hlb_r : -INFINITY;                \
        float mx_ = lv_; int am_ = lane & 15;                               \
        _Pragma("unroll")                                                   \
        for (int m_ = 8; m_; m_ >>= 1) {                                    \
            float ov_ = __shfl_xor(mx_, m_);                                \
            int oa_ = __shfl_xor(am_, m_);                                  \
            if (ov_ > mx_ || (ov_ == mx_ && oa_ < am_)) { mx_ = ov_; am_ = oa_; } \
        }                                                                   \
        float e_ = (lane < NC_) ? __expf(lv_ - mx_) : 0.f;                  \
        float se_ = e_;                                                     \
        _Pragma("unroll")                                                   \
        for (int m_ = 8; m_; m_ >>= 1) se_ += __shfl_xor(se_, m_);          \
        if (w0 && lane < NC_) {                                             \
            float lse_ = mx_ + __logf(se_);                                 \
            out[((size_t)(TPREV) * B_ + b) * NC_ + lane] = lv_ - lse_;      \
        }                                                                   \
        prev = __shfl(am_, 0);                                              \
    }

#define DEC_SUB(GA0, GA1, GA2, NB0, NB1, NB2, TC)                           \
    {                                                                       \
        float ar = 0.f, az = 0.f, an = 0.f;                                 \
        if (mv && (TC) < S_) {                                              \
            if (q == 0 && (TC) + 1 < S_) {                                  \
                const float* gg_ = gi_lin + ((size_t)((TC) + 1) * B_ + b) * G3; \
                NB0 = gg_[j]; NB1 = gg_[100 + j]; NB2 = gg_[200 + j];       \
            }                                                               \
            MATVEC_REG(hhalf[p])                                            \
        }                                                                   \
        if ((TC) >= 1) DEC_LOGITS((TC) - 1)                                 \
        if (mv && (TC) < S_ && q == 0) {                                    \
            const float* tcp_ = tc_s + prev * G3;                           \
            float r = sigmoidf_(GA0 + tcp_[j]       + ar + bhr);            \
            float z = sigmoidf_(GA1 + tcp_[100 + j] + az + bhz);            \
            float n = tanhf_(   GA2 + tcp_[200 + j] + r * (an + bhn));      \
            float hn = (1.f - z) * n + z * hc;                              \
            hc = hn;                                                        \
            hf[p ^ 1][j] = hn;                                              \
            hhalf[p ^ 1][j] = (_Float16)hn;                                 \
        }                                                                   \
        __syncthreads();                                                    \
        p ^= 1;                                                             \
    }

__global__ __launch_bounds__(DECT, 1) void dec_scan(
    const float* __restrict__ gi_lin, const unsigned* __restrict__ wpack,
    const float* __restrict__ bhh, const float* __restrict__ tcg,
    const float* __restrict__ h2lw, const float* __restrict__ h2lb,
    const float* __restrict__ hT, float* __restrict__ out)
{
    __shared__ float tc_s[NC_ * G3];
    __shared__ float hl_s[NC_ * H_];
    __shared__ __align__(8) _Float16 hhalf[2][104];
    __shared__ __align__(16) float hf[2][104];

    int bid = blockIdx.x;
    bool writer = bid < 64;
    int b = bid & 63;
    int tid = threadIdx.x;
    int j = tid >> 2, q = tid & 3;
    bool mv = tid < 400;
    int lane = tid & 63;
    bool w0 = writer && (tid < 64);

    for (int idx = tid; idx < NC_ * G3; idx += DECT) tc_s[idx] = tcg[idx];
    for (int idx = tid; idx < NC_ * H_; idx += DECT) hl_s[idx] = h2lw[idx];
    if (tid < 104) {
        float hv = (tid < H_) ? hT[b * H_ + tid] : 0.f;
        hf[0][tid] = hv;            hf[1][tid] = 0.f;
        hhalf[0][tid] = (_Float16)hv; hhalf[1][tid] = (_Float16)0.f;
    }
    LOAD_WREGS(wpack + 32000)
    float bhr = 0.f, bhz = 0.f, bhn = 0.f, hc = 0.f;
    float pA0 = 0.f, pA1 = 0.f, pA2 = 0.f, pB0 = 0.f, pB1 = 0.f, pB2 = 0.f;
    if (mv && q == 0) {
        bhr = bhh[j]; bhz = bhh[100 + j]; bhn = bhh[200 + j];
        hc = hT[b * H_ + j];
        const float* gg = gi_lin + ((size_t)0 * B_ + b) * G3;
        pA0 = gg[j]; pA1 = gg[100 + j]; pA2 = gg[200 + j];
    }
    float hlb_r = (lane < NC_) ? h2lb[lane] : 0.f;
    int prev = 0;
    __syncthreads();

    int p = 0;
    // prologue t=0 (uses pA, prefetches t=1 -> pB)
    DEC_SUB(pA0, pA1, pA2, pB0, pB1, pB2, 0)
    // t = 1..32 as 16 double-steps (odd t uses pB, even t uses pA)
    for (int it = 0; it < 16; ++it) {
        int tA = 2 * it + 1, tB = 2 * it + 2;
        DEC_SUB(pB0, pB1, pB2, pA0, pA1, pA2, tA)
        DEC_SUB(pA0, pA1, pA2, pB0, pB1, pB2, tB)
    }
}

// ---------------------------------------------------------------------------
extern "C" void kernel_launch(void* const* d_in, const int* in_sizes, int n_in,
                              void* d_out, int out_size, void* d_ws, size_t ws_size,
                              hipStream_t stream)
{
    const float* hs   = (const float*)d_in[0];
    const int*   cb   = (const int*)  d_in[1];
    const float* fc5w = (const float*)d_in[2];
    const float* fc5b = (const float*)d_in[3];
    const float* ewif = (const float*)d_in[4];
    const float* ewhf = (const float*)d_in[5];
    const float* ebif = (const float*)d_in[6];
    const float* ebhf = (const float*)d_in[7];
    const float* ewib = (const float*)d_in[8];
    const float* ewhb = (const float*)d_in[9];
    const float* ebib = (const float*)d_in[10];
    const float* ebhb = (const float*)d_in[11];
    const float* emb  = (const float*)d_in[12];
    const float* l1w  = (const float*)d_in[13];
    const float* l1b  = (const float*)d_in[14];
    const float* dwih = (const float*)d_in[15];
    const float* dwhh = (const float*)d_in[16];
    const float* dbih = (const float*)d_in[17];
    const float* dbhh = (const float*)d_in[18];
    const float* h2lw = (const float*)d_in[19];
    const float* h2lb = (const float*)d_in[20];
    float* out = (float*)d_out;

    float* ws   = (float*)d_ws;
    float* doc  = ws;                  // [32*64, 768]   = 1572864
    float* gi   = doc  + 1572864;      // [2048, 600]    = 1228800
    float* out1 = gi   + 1228800;      // [2048, 200]    = 409600
    float* hT   = out1 + 409600;       // [64, 100]      = 6400
    float* W2   = hT   + 6400;         // [300, 200]     = 60000
    float* b2   = W2   + 60000;        // [300]
    float* tcg  = b2   + 320;          // [10, 300]      = 3000
    float* gil  = tcg  + 3072;         // [2048, 300]    = 614400
    unsigned* wpack = (unsigned*)(gil + 614400);  // 3 * 16000 dwords

    pool_kernel<<<dim3(S_, B_), 256, 0, stream>>>(hs, cb, fc5w, fc5b, doc);
    w2_precompute<<<G3, 256, 0, stream>>>(dwih, l1w, l1b, emb, dbih, W2, b2, tcg);
    pack_whh<<<3, 400, 0, stream>>>(ewhf, ewhb, dwhh, wpack);
    gemm_enc<<<dim3(10, 32), 256, 0, stream>>>(doc, ewif, ewib, ebif, ebib, gi);
    enc_scan<<<256, ENCT, 0, stream>>>(gi, wpack, ebhf, ebhb, out1, hT);
    gemm_gil<<<dim3(5, 32), 256, 0, stream>>>(out1, W2, b2, gil);
    dec_scan<<<256, DECT, 0, stream>>>(gil, wpack, dbhh, tcg,
                                       h2lw, h2lb, hT, out);
}

// Round 14
// 178.103 us; speedup vs baseline: 1.6017x; 1.0929x over previous
//
#include <hip/hip_runtime.h>
#include <hip/hip_bf16.h>
#include <math.h>

#define B_ 64
#define L_ 512
#define D_ 768
#define J_ 31
#define S_ 32
#define H_ 100
#define G3 300
#define NC_ 10
#define EMB_ 50

__device__ __forceinline__ float sigmoidf_(float x) { return 1.0f / (1.0f + __expf(-x)); }
__device__ __forceinline__ float tanhf_(float x) {
    float e = __expf(2.0f * x);
    return 1.0f - 2.0f / (e + 1.0f);
}
__device__ __forceinline__ float dot4f_(float4 a, float4 b) {
    return a.x * b.x + a.y * b.y + a.z * b.z + a.w * b.w;
}

typedef _Float16 half2_t __attribute__((ext_vector_type(2)));
__device__ __forceinline__ half2_t u_as_h2(unsigned u) { return __builtin_bit_cast(half2_t, u); }
__device__ __forceinline__ unsigned packh2(float a, float b) {
    half2_t p; p.x = (_Float16)a; p.y = (_Float16)b;
    return __builtin_bit_cast(unsigned, p);
}

// ---------------------------------------------------------------------------
// K1: per-clause pooling — single-pass online softmax, one barrier.
// Block (s,b), 256 threads = 4 waves.  Wave w handles tokens w, w+4, ...
// Lane owns dims {4*lane + 256*i, i=0..2} (3 coalesced float4 per token).
// ---------------------------------------------------------------------------
__global__ __launch_bounds__(256) void pool_kernel(
    const float* __restrict__ hs, const int* __restrict__ cb,
    const float* __restrict__ fc5w, const float* __restrict__ fc5b,
    float* __restrict__ doc)
{
    __shared__ __align__(16) float acc_s[4][D_];   // 12 KB
    __shared__ float m_s[4], l_s[4];

    int s = blockIdx.x, b = blockIdx.y;
    int start = (s == 0) ? 0 : cb[b * J_ + s - 1];
    int end   = (s == J_) ? L_ : cb[b * J_ + s];
    int nt = end - start;
    int tid = threadIdx.x;
    int lane = tid & 63, wv = tid >> 6;

    if (nt <= 0) {
        for (int d = tid; d < D_; d += 256) doc[((size_t)s * B_ + b) * D_ + d] = 0.f;
        return;
    }

    float4 fwv[3];
#pragma unroll
    for (int i = 0; i < 3; ++i)
        fwv[i] = *(const float4*)(fc5w + 4 * lane + 256 * i);
    float bias = fc5b[0];

    const float* base = hs + ((size_t)b * L_ + start) * D_;
    float m = -INFINITY, l = 0.f;
    float4 acc[3];
#pragma unroll
    for (int i = 0; i < 3; ++i) acc[i] = make_float4(0.f, 0.f, 0.f, 0.f);

    for (int t = wv; t < nt; t += 4) {
        const float* row = base + (size_t)t * D_;
        float4 x0 = *(const float4*)(row + 4 * lane);
        float4 x1 = *(const float4*)(row + 4 * lane + 256);
        float4 x2 = *(const float4*)(row + 4 * lane + 512);
        float p = dot4f_(x0, fwv[0]) + dot4f_(x1, fwv[1]) + dot4f_(x2, fwv[2]);
#pragma unroll
        for (int off = 32; off; off >>= 1) p += __shfl_xor(p, off);
        p += bias;                                 // score s_t (all lanes)
        if (p > m) {
            float sc = __expf(m - p);
            l *= sc;
#pragma unroll
            for (int i = 0; i < 3; ++i) {
                acc[i].x *= sc; acc[i].y *= sc; acc[i].z *= sc; acc[i].w *= sc;
            }
            m = p;
        }
        float e = __expf(p - m);
        l += e;
        acc[0].x += e * x0.x; acc[0].y += e * x0.y; acc[0].z += e * x0.z; acc[0].w += e * x0.w;
        acc[1].x += e * x1.x; acc[1].y += e * x1.y; acc[1].z += e * x1.z; acc[1].w += e * x1.w;
        acc[2].x += e * x2.x; acc[2].y += e * x2.y; acc[2].z += e * x2.z; acc[2].w += e * x2.w;
    }
#pragma unroll
    for (int i = 0; i < 3; ++i)
        *(float4*)&acc_s[wv][4 * lane + 256 * i] = acc[i];
    if (lane == 0) { m_s[wv] = m; l_s[wv] = l; }
    __syncthreads();

    // merge 4 wave-partials; thread handles dims tid, tid+256, tid+512
    float M = fmaxf(fmaxf(m_s[0], m_s[1]), fmaxf(m_s[2], m_s[3]));
    float f0 = (l_s[0] > 0.f) ? __expf(m_s[0] - M) : 0.f;
    float f1 = (l_s[1] > 0.f) ? __expf(m_s[1] - M) : 0.f;
    float f2 = (l_s[2] > 0.f) ? __expf(m_s[2] - M) : 0.f;
    float f3 = (l_s[3] > 0.f) ? __expf(m_s[3] - M) : 0.f;
    float inv = 1.f / (l_s[0] * f0 + l_s[1] * f1 + l_s[2] * f2 + l_s[3] * f3);
    float* o = doc + ((size_t)s * B_ + b) * D_;
#pragma unroll
    for (int i = 0; i < 3; ++i) {
        int d = tid + 256 * i;
        float num = acc_s[0][d] * f0 + acc_s[1][d] * f1
                  + acc_s[2][d] * f2 + acc_s[3][d] * f3;
        o[d] = num * inv;
    }
}

// ---------------------------------------------------------------------------
// K2: gi = doc @ [Wf;Wb].T + bias via f16 dot2 (pack during staging).
// ---------------------------------------------------------------------------
__global__ __launch_bounds__(256) void gemm_enc(
    const float* __restrict__ A,
    const float* __restrict__ Wf, const float* __restrict__ Wb,
    const float* __restrict__ bf_, const float* __restrict__ bb_,
    float* __restrict__ C)
{
    __shared__ __align__(16) unsigned As[16][68];
    __shared__ __align__(16) unsigned Ws[16][68];
    int n0 = blockIdx.x * 64, m0 = blockIdx.y * 64;
    int tid = threadIdx.x;
    int tx = tid & 15, ty = tid >> 4;
    int lr = tid >> 2, lk4 = tid & 3;
    float acc[4][4] = {};

    for (int kk = 0; kk < 384; kk += 16) {
        {
            const float* ap = A + ((size_t)(m0 + lr)) * D_ + (kk + lk4 * 4) * 2;
            float4 x = *(const float4*)ap;
            float4 y = *(const float4*)(ap + 4);
            As[lk4 * 4 + 0][lr] = packh2(x.x, x.y);
            As[lk4 * 4 + 1][lr] = packh2(x.z, x.w);
            As[lk4 * 4 + 2][lr] = packh2(y.x, y.y);
            As[lk4 * 4 + 3][lr] = packh2(y.z, y.w);
            int n = n0 + lr;
            float4 u = make_float4(0.f, 0.f, 0.f, 0.f);
            float4 v = make_float4(0.f, 0.f, 0.f, 0.f);
            if (n < G3) {
                const float* wp = Wf + (size_t)n * D_ + (kk + lk4 * 4) * 2;
                u = *(const float4*)wp; v = *(const float4*)(wp + 4);
            } else if (n < 600) {
                const float* wp = Wb + (size_t)(n - G3) * D_ + (kk + lk4 * 4) * 2;
                u = *(const float4*)wp; v = *(const float4*)(wp + 4);
            }
            Ws[lk4 * 4 + 0][lr] = packh2(u.x, u.y);
            Ws[lk4 * 4 + 1][lr] = packh2(u.z, u.w);
            Ws[lk4 * 4 + 2][lr] = packh2(v.x, v.y);
            Ws[lk4 * 4 + 3][lr] = packh2(v.z, v.w);
        }
        __syncthreads();
#pragma unroll
        for (int ku = 0; ku < 16; ++ku) {
            uint4 av = *(const uint4*)&As[ku][ty * 4];
            uint4 wv = *(const uint4*)&Ws[ku][tx * 4];
            unsigned aa[4] = {av.x, av.y, av.z, av.w};
            unsigned ww[4] = {wv.x, wv.y, wv.z, wv.w};
#pragma unroll
            for (int i = 0; i < 4; ++i)
#pragma unroll
                for (int jj = 0; jj < 4; ++jj)
                    acc[i][jj] = __builtin_amdgcn_fdot2(u_as_h2(aa[i]), u_as_h2(ww[jj]),
                                                        acc[i][jj], false);
        }
        __syncthreads();
    }
#pragma unroll
    for (int jj = 0; jj < 4; ++jj) {
        int n = n0 + tx * 4 + jj;
        if (n >= 600) continue;
        float bias = (n < G3) ? bf_[n] : bb_[n - G3];
#pragma unroll
        for (int i = 0; i < 4; ++i) {
            int m = m0 + ty * 4 + i;
            C[(size_t)m * 600 + n] = acc[i][jj] + bias;
        }
    }
}

// ---------------------------------------------------------------------------
// K2b: gil = out1 @ W2.T + b2.  M=2048, N=300, K=200, f32 64x64 tiles.
// ---------------------------------------------------------------------------
__global__ __launch_bounds__(256) void gemm_gil(
    const float* __restrict__ A, const float* __restrict__ W,
    const float* __restrict__ bias, float* __restrict__ C)
{
    __shared__ __align__(16) float As[16][68];
    __shared__ __align__(16) float Ws[16][68];
    int n0 = blockIdx.x * 64, m0 = blockIdx.y * 64;
    int tid = threadIdx.x;
    int tx = tid & 15, ty = tid >> 4;
    int lr = tid >> 2, lk4 = tid & 3;
    float acc[4][4] = {};

    for (int kk = 0; kk < 208; kk += 16) {
        int k = kk + lk4 * 4;
        float4 av = make_float4(0.f, 0.f, 0.f, 0.f);
        if (k < 200) av = *(const float4*)(A + (size_t)(m0 + lr) * 200 + k);
        As[lk4 * 4 + 0][lr] = av.x; As[lk4 * 4 + 1][lr] = av.y;
        As[lk4 * 4 + 2][lr] = av.z; As[lk4 * 4 + 3][lr] = av.w;
        int n = n0 + lr;
        float4 wv = make_float4(0.f, 0.f, 0.f, 0.f);
        if (n < G3 && k < 200) wv = *(const float4*)(W + (size_t)n * 200 + k);
        Ws[lk4 * 4 + 0][lr] = wv.x; Ws[lk4 * 4 + 1][lr] = wv.y;
        Ws[lk4 * 4 + 2][lr] = wv.z; Ws[lk4 * 4 + 3][lr] = wv.w;
        __syncthreads();
#pragma unroll
        for (int ki = 0; ki < 16; ++ki) {
            float4 a4 = *(const float4*)&As[ki][ty * 4];
            float4 w4 = *(const float4*)&Ws[ki][tx * 4];
            float ai[4] = {a4.x, a4.y, a4.z, a4.w};
            float wj[4] = {w4.x, w4.y, w4.z, w4.w};
#pragma unroll
            for (int i = 0; i < 4; ++i)
#pragma unroll
                for (int jj = 0; jj < 4; ++jj) acc[i][jj] += ai[i] * wj[jj];
        }
        __syncthreads();
    }
#pragma unroll
    for (int jj = 0; jj < 4; ++jj) {
        int n = n0 + tx * 4 + jj;
        if (n >= G3) continue;
#pragma unroll
        for (int i = 0; i < 4; ++i) {
            int m = m0 + ty * 4 + i;
            C[(size_t)m * G3 + n] = acc[i][jj] + bias[n];
        }
    }
}

// ---------------------------------------------------------------------------
// Kpack: per-thread-contiguous packed-f16 Whh for the scans.
// ---------------------------------------------------------------------------
__global__ __launch_bounds__(400) void pack_whh(
    const float* __restrict__ wf, const float* __restrict__ wb,
    const float* __restrict__ wd, unsigned* __restrict__ wpack)
{
    int m = blockIdx.x;
    const float* whh = (m == 0) ? wf : (m == 1) ? wb : wd;
    int tid = threadIdx.x;
    int j = tid >> 2, q = tid & 3;
    unsigned* o = wpack + (size_t)m * 16000 + (size_t)tid * 40;
#pragma unroll
    for (int d = 0; d < 13; ++d) {
        int k = 2 * (13 * q + d);
        float r0 = (k < H_) ? whh[j * H_ + k] : 0.f;
        float r1 = (k + 1 < H_) ? whh[j * H_ + k + 1] : 0.f;
        float z0 = (k < H_) ? whh[(100 + j) * H_ + k] : 0.f;
        float z1 = (k + 1 < H_) ? whh[(100 + j) * H_ + k + 1] : 0.f;
        float n0 = (k < H_) ? whh[(200 + j) * H_ + k] : 0.f;
        float n1 = (k + 1 < H_) ? whh[(200 + j) * H_ + k + 1] : 0.f;
        o[d]      = packh2(r0, r1);
        o[13 + d] = packh2(z0, z1);
        o[26 + d] = packh2(n0, n1);
    }
    o[39] = 0u;
}

// ---------------------------------------------------------------------------
// Scan matvec core.
// ---------------------------------------------------------------------------
#define LOAD_WREGS(WPBASE)                                                  \
    uint4 wq[10];                                                           \
    if (mv) {                                                               \
        const uint4* wp_ = (const uint4*)((WPBASE) + (size_t)tid * 40);     \
        _Pragma("unroll")                                                   \
        for (int i = 0; i < 10; ++i) wq[i] = wp_[i];                        \
    }

#define WD(i) (((i) & 3) == 0 ? wq[(i) >> 2].x : ((i) & 3) == 1 ? wq[(i) >> 2].y \
             : ((i) & 3) == 2 ? wq[(i) >> 2].z : wq[(i) >> 2].w)

#define MATVEC_REG(PBUF)                                                    \
    {                                                                       \
        const unsigned* hh = (const unsigned*)(PBUF);                       \
        _Pragma("unroll")                                                   \
        for (int d = 0; d < 13; ++d) {                                      \
            half2_t hv = u_as_h2(hh[13 * q + d]);                           \
            ar = __builtin_amdgcn_fdot2(u_as_h2(WD(d)),      hv, ar, false); \
            az = __builtin_amdgcn_fdot2(u_as_h2(WD(13 + d)), hv, az, false); \
            an = __builtin_amdgcn_fdot2(u_as_h2(WD(26 + d)), hv, an, false); \
        }                                                                   \
        ar += __shfl_xor(ar, 1); ar += __shfl_xor(ar, 2);                   \
        az += __shfl_xor(az, 1); az += __shfl_xor(az, 2);                   \
        an += __shfl_xor(an, 1); an += __shfl_xor(an, 2);                   \
    }

// ---------------------------------------------------------------------------
// K3: encoder scans. 256 blocks (2x redundant; bid<128 writes), 448 thr,
// 1 barrier/step, unroll-2 with next-step g prefetch into named regs.
// ---------------------------------------------------------------------------
#define ENCT 448
#define ENC_SUB(GA0, GA1, GA2, NB0, NB1, NB2, SC, SN)                       \
    {                                                                       \
        if (mv) {                                                           \
            if (q == 0 && (SN) < S_) {                                      \
                int tn_ = bwd ? (S_ - 1 - (SN)) : (SN);                     \
                const float* gg_ = gi + ((size_t)tn_ * B_ + b) * 600 + goff; \
                NB0 = gg_[j]; NB1 = gg_[100 + j]; NB2 = gg_[200 + j];       \
            }                                                               \
            float ar = 0.f, az = 0.f, an = 0.f;                             \
            MATVEC_REG(hhalf[p])                                            \
            if (q == 0) {                                                   \
                int tc_ = bwd ? (S_ - 1 - (SC)) : (SC);                     \
                float r = sigmoidf_(GA0 + ar + bhr);                        \
                float z = sigmoidf_(GA1 + az + bhz);                        \
                float n = tanhf_(GA2 + r * (an + bhn));                     \
                float hn = (1.f - z) * n + z * hc;                          \
                hc = hn;                                                    \
                hhalf[p ^ 1][j] = (_Float16)hn;                             \
                if (writer) out1[((size_t)tc_ * B_ + b) * 200 + ooff + j] = hn; \
            }                                                               \
        }                                                                   \
        __syncthreads();                                                    \
        p ^= 1;                                                             \
    }

__global__ __launch_bounds__(ENCT, 1) void enc_scan(
    const float* __restrict__ gi, const unsigned* __restrict__ wpack,
    const float* __restrict__ bhh_f, const float* __restrict__ bhh_b,
    float* __restrict__ out1, float* __restrict__ hT)
{
    __shared__ __align__(8) _Float16 hhalf[2][104];

    int bid = blockIdx.x;
    bool writer = bid < 128;
    int breal = bid & 127;
    int b = breal & 63;
    bool bwd = (breal >= 64);
    const float* bhh = bwd ? bhh_b : bhh_f;
    int tid = threadIdx.x;
    int j = tid >> 2, q = tid & 3;
    bool mv = tid < 400;
    const int goff = bwd ? G3 : 0;
    const int ooff = bwd ? H_ : 0;

    if (tid < 104) { hhalf[0][tid] = (_Float16)0.f; hhalf[1][tid] = (_Float16)0.f; }
    LOAD_WREGS(wpack + (bwd ? 16000 : 0))
    float bhr = 0.f, bhz = 0.f, bhn = 0.f, hc = 0.f;
    float pA0 = 0.f, pA1 = 0.f, pA2 = 0.f, pB0 = 0.f, pB1 = 0.f, pB2 = 0.f;
    if (mv && q == 0) {
        bhr = bhh[j]; bhz = bhh[100 + j]; bhn = bhh[200 + j];
        int t0 = bwd ? (S_ - 1) : 0;
        const float* gg = gi + ((size_t)t0 * B_ + b) * 600 + goff;
        pA0 = gg[j]; pA1 = gg[100 + j]; pA2 = gg[200 + j];
    }
    __syncthreads();

    int p = 0;
    for (int step = 0; step < S_; step += 2) {
        ENC_SUB(pA0, pA1, pA2, pB0, pB1, pB2, step, step + 1)
        ENC_SUB(pB0, pB1, pB2, pA0, pA1, pA2, step + 1, step + 2)
    }
    if (writer && !bwd && mv && q == 0) hT[b * H_ + j] = hc;
}

// ---------------------------------------------------------------------------
// K4a: W2[n] = dwih[n][50:150] @ l1w ; b2[n] ; tcg[c][n] = bih[n]+emb[c].dwih[n][0:50]
// ---------------------------------------------------------------------------
__global__ __launch_bounds__(256) void w2_precompute(
    const float* __restrict__ dwih, const float* __restrict__ l1w,
    const float* __restrict__ l1b, const float* __restrict__ emb,
    const float* __restrict__ bih,
    float* __restrict__ W2, float* __restrict__ b2, float* __restrict__ tcg)
{
    __shared__ float dw_s[H_];
    int n = blockIdx.x;
    int k = threadIdx.x;
    if (k < H_) dw_s[k] = dwih[(size_t)n * 150 + 50 + k];
    __syncthreads();
    if (k < 200) {
        float acc = 0.f;
        for (int i = 0; i < H_; ++i) acc += dw_s[i] * l1w[(size_t)i * 200 + k];
        W2[(size_t)n * 200 + k] = acc;
    } else if (k == 200) {
        float acc = 0.f;
        for (int i = 0; i < H_; ++i) acc += dw_s[i] * l1b[i];
        b2[n] = acc;
    } else if (k < 211) {
        int c = k - 201;
        float acc = bih[n];
        const float* er = emb + c * EMB_;
        const float* wr = dwih + (size_t)n * 150;
        for (int e = 0; e < EMB_; ++e) acc += er[e] * wr[e];
        tcg[c * G3 + n] = acc;
    }
}

// ---------------------------------------------------------------------------
// K5: decoder scan. 256 blocks (4x redundant; bid<64 writes), 448 thr,
// 1 barrier/step, redundant per-wave logits/argmax, unroll-2 g prefetch.
// ---------------------------------------------------------------------------
#define DECT 448
#define DEC_LOGITS(TPREV)                                                   \
    {                                                                       \
        float acc_ = 0.f;                                                   \
        if (lane < 40) {                                                    \
            int c_ = lane >> 2, part_ = lane & 3;                           \
            const float* hr_ = hl_s + c_ * H_;                              \
            const float* hv_ = hf[p];                                       \
            int k0_ = 25 * part_;                                           \
            for (int k_ = k0_; k_ < k0_ + 25; ++k_) acc_ += hr_[k_] * hv_[k_]; \
            acc_ += __shfl_xor(acc_, 1);                                    \
            acc_ += __shfl_xor(acc_, 2);                                    \
        }                                                                   \
        float src_ = __shfl(acc_, (lane < NC_) ? 4 * lane : 0);             \
        float lv_ = (lane < NC_) ? src_ + hlb_r : -INFINITY;                \
        float mx_ = lv_; int am_ = lane & 15;                               \
        _Pragma("unroll")                                                   \
        for (int m_ = 8; m_; m_ >>= 1) {                                    \
            float ov_ = __shfl_xor(mx_, m_);                                \
            int oa_ = __shfl_xor(am_, m_);                                  \
            if (ov_ > mx_ || (ov_ == mx_ && oa_ < am_)) { mx_ = ov_; am_ = oa_; } \
        }                                                                   \
        float e_ = (lane < NC_) ? __expf(lv_ - mx_) : 0.f;                  \
        float se_ = e_;                                                     \
        _Pragma("unroll")                                                   \
        for (int m_ = 8; m_; m_ >>= 1) se_ += __shfl_xor(se_, m_);          \
        if (w0 && lane < NC_) {                                             \
            float lse_ = mx_ + __logf(se_);                                 \
            out[((size_t)(TPREV) * B_ + b) * NC_ + lane] = lv_ - lse_;      \
        }                                                                   \
        prev = __shfl(am_, 0);                                              \
    }

#define DEC_SUB(GA0, GA1, GA2, NB0, NB1, NB2, TC)                           \
    {                                                                       \
        float ar = 0.f, az = 0.f, an = 0.f;                                 \
        if (mv && (TC) < S_) {                                              \
            if (q == 0 && (TC) + 1 < S_) {                                  \
                const float* gg_ = gi_lin + ((size_t)((TC) + 1) * B_ + b) * G3; \
                NB0 = gg_[j]; NB1 = gg_[100 + j]; NB2 = gg_[200 + j];       \
            }                                                               \
            MATVEC_REG(hhalf[p])                                            \
        }                                                                   \
        if ((TC) >= 1) DEC_LOGITS((TC) - 1)                                 \
        if (mv && (TC) < S_ && q == 0) {                                    \
            const float* tcp_ = tc_s + prev * G3;                           \
            float r = sigmoidf_(GA0 + tcp_[j]       + ar + bhr);            \
            float z = sigmoidf_(GA1 + tcp_[100 + j] + az + bhz);            \
            float n = tanhf_(   GA2 + tcp_[200 + j] + r * (an + bhn));      \
            float hn = (1.f - z) * n + z * hc;                              \
            hc = hn;                                                        \
            hf[p ^ 1][j] = hn;                                              \
            hhalf[p ^ 1][j] = (_Float16)hn;                                 \
        }                                                                   \
        __syncthreads();                                                    \
        p ^= 1;                                                             \
    }

__global__ __launch_bounds__(DECT, 1) void dec_scan(
    const float* __restrict__ gi_lin, const unsigned* __restrict__ wpack,
    const float* __restrict__ bhh, const float* __restrict__ tcg,
    const float* __restrict__ h2lw, const float* __restrict__ h2lb,
    const float* __restrict__ hT, float* __restrict__ out)
{
    __shared__ float tc_s[NC_ * G3];
    __shared__ float hl_s[NC_ * H_];
    __shared__ __align__(8) _Float16 hhalf[2][104];
    __shared__ __align__(16) float hf[2][104];

    int bid = blockIdx.x;
    bool writer = bid < 64;
    int b = bid & 63;
    int tid = threadIdx.x;
    int j = tid >> 2, q = tid & 3;
    bool mv = tid < 400;
    int lane = tid & 63;
    bool w0 = writer && (tid < 64);

    for (int idx = tid; idx < NC_ * G3; idx += DECT) tc_s[idx] = tcg[idx];
    for (int idx = tid; idx < NC_ * H_; idx += DECT) hl_s[idx] = h2lw[idx];
    if (tid < 104) {
        float hv = (tid < H_) ? hT[b * H_ + tid] : 0.f;
        hf[0][tid] = hv;            hf[1][tid] = 0.f;
        hhalf[0][tid] = (_Float16)hv; hhalf[1][tid] = (_Float16)0.f;
    }
    LOAD_WREGS(wpack + 32000)
    float bhr = 0.f, bhz = 0.f, bhn = 0.f, hc = 0.f;
    float pA0 = 0.f, pA1 = 0.f, pA2 = 0.f, pB0 = 0.f, pB1 = 0.f, pB2 = 0.f;
    if (mv && q == 0) {
        bhr = bhh[j]; bhz = bhh[100 + j]; bhn = bhh[200 + j];
        hc = hT[b * H_ + j];
        const float* gg = gi_lin + ((size_t)0 * B_ + b) * G3;
        pA0 = gg[j]; pA1 = gg[100 + j]; pA2 = gg[200 + j];
    }
    float hlb_r = (lane < NC_) ? h2lb[lane] : 0.f;
    int prev = 0;
    __syncthreads();

    int p = 0;
    DEC_SUB(pA0, pA1, pA2, pB0, pB1, pB2, 0)
    for (int it = 0; it < 16; ++it) {
        int tA = 2 * it + 1, tB = 2 * it + 2;
        DEC_SUB(pB0, pB1, pB2, pA0, pA1, pA2, tA)
        DEC_SUB(pA0, pA1, pA2, pB0, pB1, pB2, tB)
    }
}

// ---------------------------------------------------------------------------
extern "C" void kernel_launch(void* const* d_in, const int* in_sizes, int n_in,
                              void* d_out, int out_size, void* d_ws, size_t ws_size,
                              hipStream_t stream)
{
    const float* hs   = (const float*)d_in[0];
    const int*   cb   = (const int*)  d_in[1];
    const float* fc5w = (const float*)d_in[2];
    const float* fc5b = (const float*)d_in[3];
    const float* ewif = (const float*)d_in[4];
    const float* ewhf = (const float*)d_in[5];
    const float* ebif = (const float*)d_in[6];
    const float* ebhf = (const float*)d_in[7];
    const float* ewib = (const float*)d_in[8];
    const float* ewhb = (const float*)d_in[9];
    const float* ebib = (const float*)d_in[10];
    const float* ebhb = (const float*)d_in[11];
    const float* emb  = (const float*)d_in[12];
    const float* l1w  = (const float*)d_in[13];
    const float* l1b  = (const float*)d_in[14];
    const float* dwih = (const float*)d_in[15];
    const float* dwhh = (const float*)d_in[16];
    const float* dbih = (const float*)d_in[17];
    const float* dbhh = (const float*)d_in[18];
    const float* h2lw = (const float*)d_in[19];
    const float* h2lb = (const float*)d_in[20];
    float* out = (float*)d_out;

    float* ws   = (float*)d_ws;
    float* doc  = ws;                  // [32*64, 768]   = 1572864
    float* gi   = doc  + 1572864;      // [2048, 600]    = 1228800
    float* out1 = gi   + 1228800;      // [2048, 200]    = 409600
    float* hT   = out1 + 409600;       // [64, 100]      = 6400
    float* W2   = hT   + 6400;         // [300, 200]     = 60000
    float* b2   = W2   + 60000;        // [300]
    float* tcg  = b2   + 320;          // [10, 300]      = 3000
    float* gil  = tcg  + 3072;         // [2048, 300]    = 614400
    unsigned* wpack = (unsigned*)(gil + 614400);  // 3 * 16000 dwords

    pool_kernel<<<dim3(S_, B_), 256, 0, stream>>>(hs, cb, fc5w, fc5b, doc);
    w2_precompute<<<G3, 256, 0, stream>>>(dwih, l1w, l1b, emb, dbih, W2, b2, tcg);
    pack_whh<<<3, 400, 0, stream>>>(ewhf, ewhb, dwhh, wpack);
    gemm_enc<<<dim3(10, 32), 256, 0, stream>>>(doc, ewif, ewib, ebif, ebib, gi);
    enc_scan<<<256, ENCT, 0, stream>>>(gi, wpack, ebhf, ebhb, out1, hT);
    gemm_gil<<<dim3(5, 32), 256, 0, stream>>>(out1, W2, b2, gil);
    dec_scan<<<256, DECT, 0, stream>>>(gil, wpack, dbhh, tcg,
                                       h2lw, h2lb, hT, out);
}